// Round 5
// baseline (2209.279 us; speedup 1.0000x reference)
//
#include <hip/hip_runtime.h>
#include <hip/hip_fp16.h>

// GCN: 3x (x = silu(Dinv A Dinv (x W) + b)) -> mean-pool -> relu(pooled@Wro+bro) -> log_softmax
// y = (x@W)*dinv[row] fp16; out[c] = dinv[c]*(sum_{r->c} y[r] + y[c]) + b; x' = silu(out) fp16.
// Edges grouped by 128-node target buckets via atomic-free counting sort (LDS hist + scans +
// LDS-cursor scatter, full-line writes). Aggregation: per-bucket LDS accumulators, ds_add_f32.

#define CH 128          // edge chunks
#define BSH 7           // log2(nodes per bucket)
#define BNODES 128

typedef _Float16 half8 __attribute__((ext_vector_type(8)));
typedef float float4v __attribute__((ext_vector_type(4)));

// Phase 1: per-chunk histogram over target buckets (LDS atomics only)
__global__ __launch_bounds__(256) void k_hist(const int* __restrict__ col, int E, int Ec, int NB,
                                              int* __restrict__ histG) {
    __shared__ int h[1024];
    int c = blockIdx.x, tid = threadIdx.x;
    for (int i = tid; i < NB; i += 256) h[i] = 0;
    __syncthreads();
    int lo = c * Ec, hi = min(E, lo + Ec);
    for (int e = lo + tid; e < hi; e += 256) atomicAdd(&h[col[e] >> BSH], 1);
    __syncthreads();
    for (int i = tid; i < NB; i += 256) histG[c * NB + i] = h[i];
}

// Phase 2a: for each bucket, exclusive scan across the CH=128 chunks (one wave per bucket)
__global__ void k_scanb(int* __restrict__ histG, int NB, int* __restrict__ btot) {
    int b = blockIdx.x;
    int l = threadIdx.x;  // 0..63
    int v0 = histG[l * NB + b];
    int v1 = histG[(64 + l) * NB + b];
    int p0 = v0, p1 = v1;
    for (int off = 1; off < 64; off <<= 1) {
        int t0 = __shfl_up(p0, off);
        int t1 = __shfl_up(p1, off);
        if (l >= off) { p0 += t0; p1 += t1; }
    }
    int A = __shfl(p0, 63);          // total of chunks 0..63
    int T = A + __shfl(p1, 63);      // bucket total
    histG[l * NB + b] = p0 - v0;             // exclusive offset for chunk l
    histG[(64 + l) * NB + b] = A + p1 - v1;  // exclusive offset for chunk 64+l
    if (l == 0) btot[b] = T;
}

// Phase 2b: exclusive scan of bucket totals -> bucket start offsets
__global__ void k_scant(const int* __restrict__ btot, int NB, int E, int* __restrict__ bstart) {
    __shared__ int s[1024];
    int tid = threadIdx.x;
    int v = (tid < NB) ? btot[tid] : 0;
    s[tid] = v;
    __syncthreads();
    for (int off = 1; off < 1024; off <<= 1) {
        int t = (tid >= off) ? s[tid - off] : 0;
        __syncthreads();
        s[tid] += t;
        __syncthreads();
    }
    if (tid < NB) bstart[tid] = s[tid] - v;
    if (tid == 0) bstart[NB] = E;
}

// Phase 3: scatter edges into bucket-grouped order. LDS cursors, no global atomics.
// Packed edge: bits 0..24 = source row, bits 25..31 = target's low 7 bits.
__global__ __launch_bounds__(256) void k_scatter(const int* __restrict__ col, const int* __restrict__ row,
                                                 int E, int Ec, int NB,
                                                 const int* __restrict__ histG,
                                                 const int* __restrict__ bstart,
                                                 unsigned int* __restrict__ edges) {
    __shared__ int cur[1024];
    int c = blockIdx.x, tid = threadIdx.x;
    for (int i = tid; i < NB; i += 256) cur[i] = bstart[i] + histG[c * NB + i];
    __syncthreads();
    int lo = c * Ec, hi = min(E, lo + Ec);
    for (int e = lo + tid; e < hi; e += 256) {
        int cc = col[e];
        int b = cc >> BSH;
        int pos = atomicAdd(&cur[b], 1);   // LDS atomic
        edges[pos] = (unsigned int)row[e] | ((unsigned int)(cc & (BNODES - 1)) << 25);
    }
}

// Phase 4: per-bucket degree count -> dinv (no global atomics)
__global__ __launch_bounds__(256) void k_dinvk(const unsigned int* __restrict__ edges,
                                               const int* __restrict__ bstart, int N,
                                               float* __restrict__ dinv) {
    __shared__ int cnt[BNODES];
    int b = blockIdx.x, tid = threadIdx.x;
    if (tid < BNODES) cnt[tid] = 0;
    __syncthreads();
    int lo = bstart[b], hi = bstart[b + 1];
    for (int e = lo + tid; e < hi; e += 256) atomicAdd(&cnt[edges[e] >> 25], 1);
    __syncthreads();
    int n = b * BNODES + tid;
    if (tid < BNODES && n < N) dinv[n] = rsqrtf((float)cnt[tid] + 1.0f);
}

// MFMA GEMM: yh[r] = fp16((x[r] @ W) * dinv[r]). (unchanged from round 4)
template <int IN_HALF>
__global__ __launch_bounds__(256) void k_gemm(const void* __restrict__ xin,
                                              const float* __restrict__ W,
                                              const float* __restrict__ dinv,
                                              __half* __restrict__ yh, int N) {
    __shared__ float sW[64 * 64];
    int tid = threadIdx.x;
    for (int k = tid; k < 4096; k += 256) sW[k] = W[k];
    __syncthreads();
    int lane = tid & 63, wv = tid >> 6;
    int c16 = lane & 15, kg = lane >> 4;
    half8 bf[4][2];
#pragma unroll
    for (int ct = 0; ct < 4; ++ct)
#pragma unroll
        for (int ks = 0; ks < 2; ++ks)
#pragma unroll
            for (int j = 0; j < 8; ++j)
                bf[ct][ks][j] = (_Float16)sW[(ks * 32 + kg * 8 + j) * 64 + ct * 16 + c16];

    int tiles = (N + 15) >> 4;
    for (int t = blockIdx.x * 4 + wv; t < tiles; t += gridDim.x * 4) {
        int base = t << 4;
        int arow = base + c16;
        half8 af0, af1;
        if (arow < N) {
            if (IN_HALF) {
                const __half* xh = (const __half*)xin;
                af0 = *(const half8*)(xh + (size_t)arow * 64 + kg * 8);
                af1 = *(const half8*)(xh + (size_t)arow * 64 + 32 + kg * 8);
            } else {
                const float* xf = (const float*)xin;
                float4 u0 = *(const float4*)(xf + (size_t)arow * 64 + kg * 8);
                float4 u1 = *(const float4*)(xf + (size_t)arow * 64 + kg * 8 + 4);
                float4 u2 = *(const float4*)(xf + (size_t)arow * 64 + 32 + kg * 8);
                float4 u3 = *(const float4*)(xf + (size_t)arow * 64 + 32 + kg * 8 + 4);
                af0[0]=(_Float16)u0.x; af0[1]=(_Float16)u0.y; af0[2]=(_Float16)u0.z; af0[3]=(_Float16)u0.w;
                af0[4]=(_Float16)u1.x; af0[5]=(_Float16)u1.y; af0[6]=(_Float16)u1.z; af0[7]=(_Float16)u1.w;
                af1[0]=(_Float16)u2.x; af1[1]=(_Float16)u2.y; af1[2]=(_Float16)u2.z; af1[3]=(_Float16)u2.w;
                af1[4]=(_Float16)u3.x; af1[5]=(_Float16)u3.y; af1[6]=(_Float16)u3.z; af1[7]=(_Float16)u3.w;
            }
        } else {
#pragma unroll
            for (int j = 0; j < 8; ++j) { af0[j] = (_Float16)0.f; af1[j] = (_Float16)0.f; }
        }
#pragma unroll
        for (int ct = 0; ct < 4; ++ct) {
            float4v c = {0.f, 0.f, 0.f, 0.f};
            c = __builtin_amdgcn_mfma_f32_16x16x32_f16(af0, bf[ct][0], c, 0, 0, 0);
            c = __builtin_amdgcn_mfma_f32_16x16x32_f16(af1, bf[ct][1], c, 0, 0, 0);
#pragma unroll
            for (int q = 0; q < 4; ++q) {
                int rr = base + kg * 4 + q;
                if (rr < N) yh[(size_t)rr * 64 + ct * 16 + c16] = __float2half_rn(c[q] * dinv[rr]);
            }
        }
    }
}

// Aggregation: one block per bucket. 128x64 fp32 LDS accumulators; half-wave (32 lanes) per
// edge, 4-deep unroll for MLP; ds_add_f32 accumulate; fused self-loop+dinv+bias+SiLU epilogue.
__global__ __launch_bounds__(256) void k_agg(const unsigned int* __restrict__ edges,
                                             const int* __restrict__ bstart,
                                             const __half* __restrict__ yh,
                                             const float* __restrict__ dinv,
                                             const float* __restrict__ bias,
                                             __half* __restrict__ xh, int N) {
    __shared__ float acc[BNODES][64];
    int b = blockIdx.x, tid = threadIdx.x;
    int wave = tid >> 6, lane = tid & 63;
    float* accf = &acc[0][0];
    for (int i = tid; i < BNODES * 64 / 4; i += 256) ((float4*)accf)[i] = make_float4(0.f, 0.f, 0.f, 0.f);
    __syncthreads();

    int lo = bstart[b], cnt = bstart[b + 1] - lo;
    int hw = tid >> 5;        // half-wave 0..7
    int i = tid & 31;         // feature pair
    const unsigned int* yw = (const unsigned int*)yh;

    int e = hw;
    for (; e + 24 < cnt; e += 32) {
        unsigned int p0 = edges[lo + e];
        unsigned int p1 = edges[lo + e + 8];
        unsigned int p2 = edges[lo + e + 16];
        unsigned int p3 = edges[lo + e + 24];
        unsigned int w0 = yw[(size_t)(p0 & 0x1FFFFFFu) * 32 + i];
        unsigned int w1 = yw[(size_t)(p1 & 0x1FFFFFFu) * 32 + i];
        unsigned int w2 = yw[(size_t)(p2 & 0x1FFFFFFu) * 32 + i];
        unsigned int w3 = yw[(size_t)(p3 & 0x1FFFFFFu) * 32 + i];
        float2 f0 = __half22float2(*(const __half2*)&w0);
        float2 f1 = __half22float2(*(const __half2*)&w1);
        float2 f2 = __half22float2(*(const __half2*)&w2);
        float2 f3 = __half22float2(*(const __half2*)&w3);
        atomicAdd(&acc[p0 >> 25][2 * i], f0.x); atomicAdd(&acc[p0 >> 25][2 * i + 1], f0.y);
        atomicAdd(&acc[p1 >> 25][2 * i], f1.x); atomicAdd(&acc[p1 >> 25][2 * i + 1], f1.y);
        atomicAdd(&acc[p2 >> 25][2 * i], f2.x); atomicAdd(&acc[p2 >> 25][2 * i + 1], f2.y);
        atomicAdd(&acc[p3 >> 25][2 * i], f3.x); atomicAdd(&acc[p3 >> 25][2 * i + 1], f3.y);
    }
    for (; e < cnt; e += 8) {
        unsigned int p = edges[lo + e];
        unsigned int w = yw[(size_t)(p & 0x1FFFFFFu) * 32 + i];
        float2 f = __half22float2(*(const __half2*)&w);
        atomicAdd(&acc[p >> 25][2 * i], f.x);
        atomicAdd(&acc[p >> 25][2 * i + 1], f.y);
    }
    __syncthreads();

    for (int n = wave; n < BNODES; n += 4) {
        int ng = b * BNODES + n;
        if (ng >= N) break;
        float v = acc[n][lane] + __half2float(yh[(size_t)ng * 64 + lane]);  // + self loop
        float o = dinv[ng] * v + bias[lane];
        o = o / (1.f + __expf(-o));
        xh[(size_t)ng * 64 + lane] = __float2half_rn(o);
    }
}

// One block per graph: binary-search segment, mean-pool (fp32 accum), readout, log_softmax
__global__ void k_pool_readout(const __half2* __restrict__ xh2, const int* __restrict__ batch, int N,
                               const float* __restrict__ Wro, const float* __restrict__ bro,
                               float* __restrict__ out, int C) {
    int g = blockIdx.x;
    int tid = threadIdx.x, wave = tid >> 6, lane = tid & 63;
    int grp = lane >> 5, i = lane & 31;
    __shared__ float part[4][64];
    __shared__ float pooled[64];
    __shared__ float logits[32];
    int lo = 0, hb = N;
    while (lo < hb) { int m = (lo + hb) >> 1; if (batch[m] < g) lo = m + 1; else hb = m; }
    int lo2 = lo, hi2 = N;
    while (lo2 < hi2) { int m = (lo2 + hi2) >> 1; if (batch[m] < g + 1) lo2 = m + 1; else hi2 = m; }
    int hi = lo2;
    float ax = 0.f, ay = 0.f;
    for (int r = lo + wave * 2 + grp; r < hi; r += 8) {
        float2 v = __half22float2(xh2[(size_t)r * 32 + i]);
        ax += v.x; ay += v.y;
    }
    ax += __shfl_xor(ax, 32);
    ay += __shfl_xor(ay, 32);
    if (grp == 0) { part[wave][2 * i] = ax; part[wave][2 * i + 1] = ay; }
    __syncthreads();
    if (tid < 64) {
        float cntf = fmaxf((float)(hi - lo), 1.0f);
        pooled[tid] = (part[0][tid] + part[1][tid] + part[2][tid] + part[3][tid]) / cntf;
    }
    __syncthreads();
    if (tid < C) {
        float a = bro[tid];
        for (int k = 0; k < 64; ++k) a += pooled[k] * Wro[k * C + tid];
        logits[tid] = fmaxf(a, 0.f);
    }
    __syncthreads();
    if (tid == 0) {
        float m = -1e30f;
        for (int c = 0; c < C; ++c) m = fmaxf(m, logits[c]);
        float sum = 0.f;
        for (int c = 0; c < C; ++c) sum += __expf(logits[c] - m);
        float lse = m + __logf(sum);
        for (int c = 0; c < C; ++c) out[g * C + c] = logits[c] - lse;
    }
}

static inline size_t align256(size_t v) { return (v + 255) & ~(size_t)255; }

extern "C" void kernel_launch(void* const* d_in, const int* in_sizes, int n_in,
                              void* d_out, int out_size, void* d_ws, size_t ws_size,
                              hipStream_t stream) {
    const float* x    = (const float*)d_in[0];
    const int*   ei   = (const int*)d_in[1];
    const int*   batch= (const int*)d_in[2];
    const float* W[3] = {(const float*)d_in[4], (const float*)d_in[6], (const float*)d_in[8]};
    const float* b[3] = {(const float*)d_in[5], (const float*)d_in[7], (const float*)d_in[9]};
    const float* Wro  = (const float*)d_in[10];
    const float* bro  = (const float*)d_in[11];

    int N = in_sizes[2];
    int E = in_sizes[1] / 2;
    int C = in_sizes[10] / 64;
    int G = out_size / C;

    const int* row = ei;          // sources
    const int* col = ei + E;      // targets

    int NB = (N + BNODES - 1) >> BSH;      // target buckets (<=1024)
    int Ec = (E + CH - 1) / CH;            // edges per chunk

    char* ws = (char*)d_ws;
    size_t off = 0;
    float* dinv    = (float*)(ws + off);        off = align256(off + (size_t)N * 4);
    int*   histG   = (int*)(ws + off);          off = align256(off + (size_t)CH * NB * 4);
    int*   btot    = (int*)(ws + off);          off = align256(off + (size_t)NB * 4);
    int*   bstart  = (int*)(ws + off);          off = align256(off + (size_t)(NB + 1) * 4);
    unsigned int* edges = (unsigned int*)(ws + off); off = align256(off + (size_t)E * 4);
    __half* yh     = (__half*)(ws + off);       off = align256(off + (size_t)N * 64 * 2);
    __half* xh     = (__half*)(ws + off);       off = align256(off + (size_t)N * 64 * 2);

    k_hist<<<CH, 256, 0, stream>>>(col, E, Ec, NB, histG);
    k_scanb<<<NB, 64, 0, stream>>>(histG, NB, btot);
    k_scant<<<1, 1024, 0, stream>>>(btot, NB, E, bstart);
    k_scatter<<<CH, 256, 0, stream>>>(col, row, E, Ec, NB, histG, bstart, edges);
    k_dinvk<<<NB, 256, 0, stream>>>(edges, bstart, N, dinv);

    k_gemm<0><<<512, 256, 0, stream>>>(x, W[0], dinv, yh, N);
    k_agg<<<NB, 256, 0, stream>>>(edges, bstart, yh, dinv, b[0], xh, N);
    k_gemm<1><<<512, 256, 0, stream>>>(xh, W[1], dinv, yh, N);
    k_agg<<<NB, 256, 0, stream>>>(edges, bstart, yh, dinv, b[1], xh, N);
    k_gemm<1><<<512, 256, 0, stream>>>(xh, W[2], dinv, yh, N);
    k_agg<<<NB, 256, 0, stream>>>(edges, bstart, yh, dinv, b[2], xh, N);

    k_pool_readout<<<G, 256, 0, stream>>>((const __half2*)xh, batch, N, Wro, bro, (float*)d_out, C);
}

// Round 6
// 338.866 us; speedup vs baseline: 6.5196x; 6.5196x over previous
//
#include <hip/hip_runtime.h>
#include <hip/hip_fp16.h>

// GCN: 3x (x = silu(Dinv A Dinv (x W) + b)) -> mean-pool -> relu(pooled@Wro+bro) -> log_softmax
// y = (x@W)*dinv[row] fp16; out[c] = dinv[c]*(sum_{r->c} y[r] + y[c]) + b; x' = silu(out) fp16.
// CSR built once via atomic-free two-level counting sort:
//   hist/scan/scatter -> edges grouped by 128-node bucket (LDS cursors, no global atomics)
//   k_sort2 -> per-node CSR (srcs, starts) + dinv, per-bucket LDS counting sort.
// Aggregation: wave-per-node CSR gather (8 groups x 8 lanes, 16B/lane), shfl-xor reduce.

#define CH 128          // edge chunks
#define BSH 7           // log2(nodes per bucket)
#define BNODES 128

typedef _Float16 half8 __attribute__((ext_vector_type(8)));
typedef float float4v __attribute__((ext_vector_type(4)));

// Phase 1: per-chunk histogram over target buckets (LDS atomics only)
__global__ __launch_bounds__(256) void k_hist(const int* __restrict__ col, int E, int Ec, int NB,
                                              int* __restrict__ histG) {
    __shared__ int h[1024];
    int c = blockIdx.x, tid = threadIdx.x;
    for (int i = tid; i < NB; i += 256) h[i] = 0;
    __syncthreads();
    int lo = c * Ec, hi = min(E, lo + Ec);
    for (int e = lo + tid; e < hi; e += 256) atomicAdd(&h[col[e] >> BSH], 1);
    __syncthreads();
    for (int i = tid; i < NB; i += 256) histG[c * NB + i] = h[i];
}

// Phase 2a: per bucket, exclusive scan across CH=128 chunks (one wave per bucket)
__global__ void k_scanb(int* __restrict__ histG, int NB, int* __restrict__ btot) {
    int b = blockIdx.x;
    int l = threadIdx.x;  // 0..63
    int v0 = histG[l * NB + b];
    int v1 = histG[(64 + l) * NB + b];
    int p0 = v0, p1 = v1;
    for (int off = 1; off < 64; off <<= 1) {
        int t0 = __shfl_up(p0, off);
        int t1 = __shfl_up(p1, off);
        if (l >= off) { p0 += t0; p1 += t1; }
    }
    int A = __shfl(p0, 63);          // total of chunks 0..63
    int T = A + __shfl(p1, 63);      // bucket total
    histG[l * NB + b] = p0 - v0;             // exclusive offset for chunk l
    histG[(64 + l) * NB + b] = A + p1 - v1;  // exclusive offset for chunk 64+l
    if (l == 0) btot[b] = T;
}

// Phase 2b: exclusive scan of bucket totals -> bucket start offsets
__global__ void k_scant(const int* __restrict__ btot, int NB, int E, int* __restrict__ bstart) {
    __shared__ int s[1024];
    int tid = threadIdx.x;
    int v = (tid < NB) ? btot[tid] : 0;
    s[tid] = v;
    __syncthreads();
    for (int off = 1; off < 1024; off <<= 1) {
        int t = (tid >= off) ? s[tid - off] : 0;
        __syncthreads();
        s[tid] += t;
        __syncthreads();
    }
    if (tid < NB) bstart[tid] = s[tid] - v;
    if (tid == 0) bstart[NB] = E;
}

// Phase 3: scatter edges into bucket-grouped order. LDS cursors, no global atomics.
// Packed edge: bits 0..24 = source row, bits 25..31 = target's low 7 bits.
__global__ __launch_bounds__(256) void k_scatter(const int* __restrict__ col, const int* __restrict__ row,
                                                 int E, int Ec, int NB,
                                                 const int* __restrict__ histG,
                                                 const int* __restrict__ bstart,
                                                 unsigned int* __restrict__ edges) {
    __shared__ int cur[1024];
    int c = blockIdx.x, tid = threadIdx.x;
    for (int i = tid; i < NB; i += 256) cur[i] = bstart[i] + histG[c * NB + i];
    __syncthreads();
    int lo = c * Ec, hi = min(E, lo + Ec);
    for (int e = lo + tid; e < hi; e += 256) {
        int cc = col[e];
        int b = cc >> BSH;
        int pos = atomicAdd(&cur[b], 1);   // LDS atomic
        edges[pos] = (unsigned int)row[e] | ((unsigned int)(cc & (BNODES - 1)) << 25);
    }
}

// Phase 4: within each bucket, counting-sort edges by local node -> per-node CSR + dinv.
__global__ __launch_bounds__(256) void k_sort2(const unsigned int* __restrict__ edges,
                                               const int* __restrict__ bstart, int N, int E, int NB,
                                               int* __restrict__ srcs, int* __restrict__ starts,
                                               float* __restrict__ dinv) {
    __shared__ int cnt[BNODES];
    __shared__ int cur[BNODES];
    int b = blockIdx.x, tid = threadIdx.x;
    if (tid < BNODES) cnt[tid] = 0;
    __syncthreads();
    int lo = bstart[b], hi = bstart[b + 1];
    for (int e = lo + tid; e < hi; e += 256) atomicAdd(&cnt[edges[e] >> 25], 1);
    __syncthreads();
    if (tid < 64) {   // wave 0: exclusive scan of cnt[128], 2 elems/lane
        int v0 = cnt[tid], v1 = cnt[64 + tid];
        int p0 = v0, p1 = v1;
        for (int off = 1; off < 64; off <<= 1) {
            int t0 = __shfl_up(p0, off);
            int t1 = __shfl_up(p1, off);
            if (tid >= off) { p0 += t0; p1 += t1; }
        }
        int A = __shfl(p0, 63);
        cur[tid] = lo + p0 - v0;
        cur[64 + tid] = lo + A + p1 - v1;
    }
    __syncthreads();
    int ng = b * BNODES + tid;
    if (tid < BNODES && ng < N) {
        starts[ng] = cur[tid];
        dinv[ng] = rsqrtf((float)cnt[tid] + 1.0f);
    }
    if (b == 0 && tid == 0) starts[N] = E;
    __syncthreads();   // starts must be read out before cursors move
    for (int e = lo + tid; e < hi; e += 256) {
        unsigned int p = edges[e];
        int pos = atomicAdd(&cur[p >> 25], 1);   // LDS atomic
        srcs[pos] = (int)(p & 0x1FFFFFFu);
    }
}

// MFMA GEMM: yh[r] = fp16((x[r] @ W) * dinv[r]).
template <int IN_HALF>
__global__ __launch_bounds__(256) void k_gemm(const void* __restrict__ xin,
                                              const float* __restrict__ W,
                                              const float* __restrict__ dinv,
                                              __half* __restrict__ yh, int N) {
    __shared__ float sW[64 * 64];
    int tid = threadIdx.x;
    for (int k = tid; k < 4096; k += 256) sW[k] = W[k];
    __syncthreads();
    int lane = tid & 63, wv = tid >> 6;
    int c16 = lane & 15, kg = lane >> 4;
    half8 bf[4][2];
#pragma unroll
    for (int ct = 0; ct < 4; ++ct)
#pragma unroll
        for (int ks = 0; ks < 2; ++ks)
#pragma unroll
            for (int j = 0; j < 8; ++j)
                bf[ct][ks][j] = (_Float16)sW[(ks * 32 + kg * 8 + j) * 64 + ct * 16 + c16];

    int tiles = (N + 15) >> 4;
    for (int t = blockIdx.x * 4 + wv; t < tiles; t += gridDim.x * 4) {
        int base = t << 4;
        int arow = base + c16;
        half8 af0, af1;
        if (arow < N) {
            if (IN_HALF) {
                const __half* xh = (const __half*)xin;
                af0 = *(const half8*)(xh + (size_t)arow * 64 + kg * 8);
                af1 = *(const half8*)(xh + (size_t)arow * 64 + 32 + kg * 8);
            } else {
                const float* xf = (const float*)xin;
                float4 u0 = *(const float4*)(xf + (size_t)arow * 64 + kg * 8);
                float4 u1 = *(const float4*)(xf + (size_t)arow * 64 + kg * 8 + 4);
                float4 u2 = *(const float4*)(xf + (size_t)arow * 64 + 32 + kg * 8);
                float4 u3 = *(const float4*)(xf + (size_t)arow * 64 + 32 + kg * 8 + 4);
                af0[0]=(_Float16)u0.x; af0[1]=(_Float16)u0.y; af0[2]=(_Float16)u0.z; af0[3]=(_Float16)u0.w;
                af0[4]=(_Float16)u1.x; af0[5]=(_Float16)u1.y; af0[6]=(_Float16)u1.z; af0[7]=(_Float16)u1.w;
                af1[0]=(_Float16)u2.x; af1[1]=(_Float16)u2.y; af1[2]=(_Float16)u2.z; af1[3]=(_Float16)u2.w;
                af1[4]=(_Float16)u3.x; af1[5]=(_Float16)u3.y; af1[6]=(_Float16)u3.z; af1[7]=(_Float16)u3.w;
            }
        } else {
#pragma unroll
            for (int j = 0; j < 8; ++j) { af0[j] = (_Float16)0.f; af1[j] = (_Float16)0.f; }
        }
#pragma unroll
        for (int ct = 0; ct < 4; ++ct) {
            float4v c = {0.f, 0.f, 0.f, 0.f};
            c = __builtin_amdgcn_mfma_f32_16x16x32_f16(af0, bf[ct][0], c, 0, 0, 0);
            c = __builtin_amdgcn_mfma_f32_16x16x32_f16(af1, bf[ct][1], c, 0, 0, 0);
#pragma unroll
            for (int q = 0; q < 4; ++q) {
                int rr = base + kg * 4 + q;
                if (rr < N) yh[(size_t)rr * 64 + ct * 16 + c16] = __float2half_rn(c[q] * dinv[rr]);
            }
        }
    }
}

// One wave per node. 8 groups x 8 lanes; lane (g,i) loads 16B chunk i of row srcs[e+g]
// -> 8 rows per wave-instruction, 16 rows in flight per iteration. shfl-xor reduce.
__global__ __launch_bounds__(256) void k_agg(const int* __restrict__ starts,
                                             const int* __restrict__ srcs,
                                             const __half* __restrict__ yh,
                                             const float* __restrict__ dinv,
                                             const float* __restrict__ b,
                                             __half* __restrict__ xh, int N) {
    int wid = (blockIdx.x * blockDim.x + threadIdx.x) >> 6;
    if (wid >= N) return;
    int lane = threadIdx.x & 63;
    int g = lane >> 3, i = lane & 7;
    const float4* y4 = (const float4*)yh;   // row = 8 float4 chunks
    float acc[8] = {0.f,0.f,0.f,0.f,0.f,0.f,0.f,0.f};

    if (g == 0) {  // self loop
        float4 raw = y4[(size_t)wid * 8 + i];
        const __half2* h = (const __half2*)&raw;
#pragma unroll
        for (int p = 0; p < 4; ++p) {
            float2 f = __half22float2(h[p]);
            acc[2 * p] += f.x; acc[2 * p + 1] += f.y;
        }
    }
    int s = starts[wid], t = starts[wid + 1];
    for (int e = s; e < t; e += 16) {
        int e0 = e + g, e1 = e + 8 + g;
        if (e0 < t) {
            float4 raw = y4[(size_t)srcs[e0] * 8 + i];
            const __half2* h = (const __half2*)&raw;
#pragma unroll
            for (int p = 0; p < 4; ++p) {
                float2 f = __half22float2(h[p]);
                acc[2 * p] += f.x; acc[2 * p + 1] += f.y;
            }
        }
        if (e1 < t) {
            float4 raw = y4[(size_t)srcs[e1] * 8 + i];
            const __half2* h = (const __half2*)&raw;
#pragma unroll
            for (int p = 0; p < 4; ++p) {
                float2 f = __half22float2(h[p]);
                acc[2 * p] += f.x; acc[2 * p + 1] += f.y;
            }
        }
    }
#pragma unroll
    for (int off = 8; off <= 32; off <<= 1)
#pragma unroll
        for (int f = 0; f < 8; ++f) acc[f] += __shfl_xor(acc[f], off);

    if (g == 0) {
        float d = dinv[wid];
        float4 b0 = ((const float4*)b)[2 * i];
        float4 b1 = ((const float4*)b)[2 * i + 1];
        float bb[8] = {b0.x, b0.y, b0.z, b0.w, b1.x, b1.y, b1.z, b1.w};
        float o[8];
#pragma unroll
        for (int f = 0; f < 8; ++f) {
            float v = d * acc[f] + bb[f];
            o[f] = v / (1.f + __expf(-v));
        }
        float4 outv;
        __half2* oh = (__half2*)&outv;
#pragma unroll
        for (int p = 0; p < 4; ++p) oh[p] = __float22half2_rn(make_float2(o[2 * p], o[2 * p + 1]));
        ((float4*)xh)[(size_t)wid * 8 + i] = outv;
    }
}

// One block per graph: binary-search segment, mean-pool (fp32 accum), readout, log_softmax
__global__ void k_pool_readout(const __half2* __restrict__ xh2, const int* __restrict__ batch, int N,
                               const float* __restrict__ Wro, const float* __restrict__ bro,
                               float* __restrict__ out, int C) {
    int g = blockIdx.x;
    int tid = threadIdx.x, wave = tid >> 6, lane = tid & 63;
    int grp = lane >> 5, i = lane & 31;
    __shared__ float part[4][64];
    __shared__ float pooled[64];
    __shared__ float logits[32];
    int lo = 0, hb = N;
    while (lo < hb) { int m = (lo + hb) >> 1; if (batch[m] < g) lo = m + 1; else hb = m; }
    int lo2 = lo, hi2 = N;
    while (lo2 < hi2) { int m = (lo2 + hi2) >> 1; if (batch[m] < g + 1) lo2 = m + 1; else hi2 = m; }
    int hi = lo2;
    float ax = 0.f, ay = 0.f;
    for (int r = lo + wave * 2 + grp; r < hi; r += 8) {
        float2 v = __half22float2(xh2[(size_t)r * 32 + i]);
        ax += v.x; ay += v.y;
    }
    ax += __shfl_xor(ax, 32);
    ay += __shfl_xor(ay, 32);
    if (grp == 0) { part[wave][2 * i] = ax; part[wave][2 * i + 1] = ay; }
    __syncthreads();
    if (tid < 64) {
        float cntf = fmaxf((float)(hi - lo), 1.0f);
        pooled[tid] = (part[0][tid] + part[1][tid] + part[2][tid] + part[3][tid]) / cntf;
    }
    __syncthreads();
    if (tid < C) {
        float a = bro[tid];
        for (int k = 0; k < 64; ++k) a += pooled[k] * Wro[k * C + tid];
        logits[tid] = fmaxf(a, 0.f);
    }
    __syncthreads();
    if (tid == 0) {
        float m = -1e30f;
        for (int c = 0; c < C; ++c) m = fmaxf(m, logits[c]);
        float sum = 0.f;
        for (int c = 0; c < C; ++c) sum += __expf(logits[c] - m);
        float lse = m + __logf(sum);
        for (int c = 0; c < C; ++c) out[g * C + c] = logits[c] - lse;
    }
}

static inline size_t align256(size_t v) { return (v + 255) & ~(size_t)255; }

extern "C" void kernel_launch(void* const* d_in, const int* in_sizes, int n_in,
                              void* d_out, int out_size, void* d_ws, size_t ws_size,
                              hipStream_t stream) {
    const float* x    = (const float*)d_in[0];
    const int*   ei   = (const int*)d_in[1];
    const int*   batch= (const int*)d_in[2];
    const float* W[3] = {(const float*)d_in[4], (const float*)d_in[6], (const float*)d_in[8]};
    const float* b[3] = {(const float*)d_in[5], (const float*)d_in[7], (const float*)d_in[9]};
    const float* Wro  = (const float*)d_in[10];
    const float* bro  = (const float*)d_in[11];

    int N = in_sizes[2];
    int E = in_sizes[1] / 2;
    int C = in_sizes[10] / 64;
    int G = out_size / C;

    const int* row = ei;          // sources
    const int* col = ei + E;      // targets

    int NB = (N + BNODES - 1) >> BSH;      // target buckets (<=1024)
    int Ec = (E + CH - 1) / CH;            // edges per chunk

    char* ws = (char*)d_ws;
    size_t off = 0;
    float* dinv    = (float*)(ws + off);        off = align256(off + (size_t)N * 4);
    int*   histG   = (int*)(ws + off);          off = align256(off + (size_t)CH * NB * 4);
    int*   btot    = (int*)(ws + off);          off = align256(off + (size_t)NB * 4);
    int*   bstart  = (int*)(ws + off);          off = align256(off + (size_t)(NB + 1) * 4);
    unsigned int* edges = (unsigned int*)(ws + off); off = align256(off + (size_t)E * 4);
    int*   srcs    = (int*)(ws + off);          off = align256(off + (size_t)E * 4);
    int*   starts  = (int*)(ws + off);          off = align256(off + (size_t)(N + 1) * 4);
    __half* yh     = (__half*)(ws + off);       off = align256(off + (size_t)N * 64 * 2);
    __half* xh     = (__half*)(ws + off);       off = align256(off + (size_t)N * 64 * 2);

    k_hist<<<CH, 256, 0, stream>>>(col, E, Ec, NB, histG);
    k_scanb<<<NB, 64, 0, stream>>>(histG, NB, btot);
    k_scant<<<1, 1024, 0, stream>>>(btot, NB, E, bstart);
    k_scatter<<<CH, 256, 0, stream>>>(col, row, E, Ec, NB, histG, bstart, edges);
    k_sort2<<<NB, 256, 0, stream>>>(edges, bstart, N, E, NB, srcs, starts, dinv);

    int aggB = (N + 3) / 4;   // 4 waves (nodes) per 256-thread block

    k_gemm<0><<<512, 256, 0, stream>>>(x, W[0], dinv, yh, N);
    k_agg<<<aggB, 256, 0, stream>>>(starts, srcs, yh, dinv, b[0], xh, N);
    k_gemm<1><<<512, 256, 0, stream>>>(xh, W[1], dinv, yh, N);
    k_agg<<<aggB, 256, 0, stream>>>(starts, srcs, yh, dinv, b[1], xh, N);
    k_gemm<1><<<512, 256, 0, stream>>>(xh, W[2], dinv, yh, N);
    k_agg<<<aggB, 256, 0, stream>>>(starts, srcs, yh, dinv, b[2], xh, N);

    k_pool_readout<<<G, 256, 0, stream>>>((const __half2*)xh, batch, N, Wro, bro, (float*)d_out, C);
}

// Round 7
// 303.852 us; speedup vs baseline: 7.2709x; 1.1152x over previous
//
#include <hip/hip_runtime.h>
#include <hip/hip_fp16.h>

// GCN: 3x (x = silu(Dinv A Dinv (x W) + b)) -> mean-pool -> relu(pooled@Wro+bro) -> log_softmax
// y = (x@W)*dinv[row] fp16; out[c] = dinv[c]*(sum_{r->c} y[r] + y[c]) + b; x' = silu(out) fp16.
// CSR built once via atomic-free two-level counting sort (bucket hist/scan/scatter + in-bucket sort).
// Aggregation: wave-per-node CSR gather, packed v_pk_add_f16 accumulation, fp32 epilogue.

#define CH 128          // edge chunks
#define BSH 7           // log2(nodes per bucket)
#define BNODES 128

typedef _Float16 half8 __attribute__((ext_vector_type(8)));
typedef float float4v __attribute__((ext_vector_type(4)));

// Phase 1: per-chunk histogram over target buckets (LDS atomics only)
__global__ __launch_bounds__(256) void k_hist(const int* __restrict__ col, int E, int Ec, int NB,
                                              int* __restrict__ histG) {
    __shared__ int h[1024];
    int c = blockIdx.x, tid = threadIdx.x;
    for (int i = tid; i < NB; i += 256) h[i] = 0;
    __syncthreads();
    int lo = c * Ec, hi = min(E, lo + Ec);
    for (int e = lo + tid; e < hi; e += 256) atomicAdd(&h[col[e] >> BSH], 1);
    __syncthreads();
    for (int i = tid; i < NB; i += 256) histG[c * NB + i] = h[i];
}

// Phase 2a: per bucket, exclusive scan across CH=128 chunks (one wave per bucket)
__global__ void k_scanb(int* __restrict__ histG, int NB, int* __restrict__ btot) {
    int b = blockIdx.x;
    int l = threadIdx.x;  // 0..63
    int v0 = histG[l * NB + b];
    int v1 = histG[(64 + l) * NB + b];
    int p0 = v0, p1 = v1;
    for (int off = 1; off < 64; off <<= 1) {
        int t0 = __shfl_up(p0, off);
        int t1 = __shfl_up(p1, off);
        if (l >= off) { p0 += t0; p1 += t1; }
    }
    int A = __shfl(p0, 63);          // total of chunks 0..63
    int T = A + __shfl(p1, 63);      // bucket total
    histG[l * NB + b] = p0 - v0;             // exclusive offset for chunk l
    histG[(64 + l) * NB + b] = A + p1 - v1;  // exclusive offset for chunk 64+l
    if (l == 0) btot[b] = T;
}

// Phase 2b: exclusive scan of bucket totals -> bucket start offsets
__global__ void k_scant(const int* __restrict__ btot, int NB, int E, int* __restrict__ bstart) {
    __shared__ int s[1024];
    int tid = threadIdx.x;
    int v = (tid < NB) ? btot[tid] : 0;
    s[tid] = v;
    __syncthreads();
    for (int off = 1; off < 1024; off <<= 1) {
        int t = (tid >= off) ? s[tid - off] : 0;
        __syncthreads();
        s[tid] += t;
        __syncthreads();
    }
    if (tid < NB) bstart[tid] = s[tid] - v;
    if (tid == 0) bstart[NB] = E;
}

// Phase 3: scatter edges into bucket-grouped order. LDS cursors, no global atomics.
// Packed edge: bits 0..24 = source row, bits 25..31 = target's low 7 bits.
__global__ __launch_bounds__(256) void k_scatter(const int* __restrict__ col, const int* __restrict__ row,
                                                 int E, int Ec, int NB,
                                                 const int* __restrict__ histG,
                                                 const int* __restrict__ bstart,
                                                 unsigned int* __restrict__ edges) {
    __shared__ int cur[1024];
    int c = blockIdx.x, tid = threadIdx.x;
    for (int i = tid; i < NB; i += 256) cur[i] = bstart[i] + histG[c * NB + i];
    __syncthreads();
    int lo = c * Ec, hi = min(E, lo + Ec);
    for (int e = lo + tid; e < hi; e += 256) {
        int cc = col[e];
        int b = cc >> BSH;
        int pos = atomicAdd(&cur[b], 1);   // LDS atomic
        edges[pos] = (unsigned int)row[e] | ((unsigned int)(cc & (BNODES - 1)) << 25);
    }
}

// Phase 4: within each bucket, counting-sort edges by local node -> per-node CSR + dinv.
__global__ __launch_bounds__(256) void k_sort2(const unsigned int* __restrict__ edges,
                                               const int* __restrict__ bstart, int N, int E, int NB,
                                               int* __restrict__ srcs, int* __restrict__ starts,
                                               float* __restrict__ dinv) {
    __shared__ int cnt[BNODES];
    __shared__ int cur[BNODES];
    int b = blockIdx.x, tid = threadIdx.x;
    if (tid < BNODES) cnt[tid] = 0;
    __syncthreads();
    int lo = bstart[b], hi = bstart[b + 1];
    for (int e = lo + tid; e < hi; e += 256) atomicAdd(&cnt[edges[e] >> 25], 1);
    __syncthreads();
    if (tid < 64) {   // wave 0: exclusive scan of cnt[128], 2 elems/lane
        int v0 = cnt[tid], v1 = cnt[64 + tid];
        int p0 = v0, p1 = v1;
        for (int off = 1; off < 64; off <<= 1) {
            int t0 = __shfl_up(p0, off);
            int t1 = __shfl_up(p1, off);
            if (tid >= off) { p0 += t0; p1 += t1; }
        }
        int A = __shfl(p0, 63);
        cur[tid] = lo + p0 - v0;
        cur[64 + tid] = lo + A + p1 - v1;
    }
    __syncthreads();
    int ng = b * BNODES + tid;
    if (tid < BNODES && ng < N) {
        starts[ng] = cur[tid];
        dinv[ng] = rsqrtf((float)cnt[tid] + 1.0f);
    }
    if (b == 0 && tid == 0) starts[N] = E;
    __syncthreads();   // starts must be read out before cursors move
    for (int e = lo + tid; e < hi; e += 256) {
        unsigned int p = edges[e];
        int pos = atomicAdd(&cur[p >> 25], 1);   // LDS atomic
        srcs[pos] = (int)(p & 0x1FFFFFFu);
    }
}

// MFMA GEMM: yh[r] = fp16((x[r] @ W) * dinv[r]).
template <int IN_HALF>
__global__ __launch_bounds__(256) void k_gemm(const void* __restrict__ xin,
                                              const float* __restrict__ W,
                                              const float* __restrict__ dinv,
                                              __half* __restrict__ yh, int N) {
    __shared__ float sW[64 * 64];
    int tid = threadIdx.x;
    for (int k = tid; k < 4096; k += 256) sW[k] = W[k];
    __syncthreads();
    int lane = tid & 63, wv = tid >> 6;
    int c16 = lane & 15, kg = lane >> 4;
    half8 bf[4][2];
#pragma unroll
    for (int ct = 0; ct < 4; ++ct)
#pragma unroll
        for (int ks = 0; ks < 2; ++ks)
#pragma unroll
            for (int j = 0; j < 8; ++j)
                bf[ct][ks][j] = (_Float16)sW[(ks * 32 + kg * 8 + j) * 64 + ct * 16 + c16];

    int tiles = (N + 15) >> 4;
    for (int t = blockIdx.x * 4 + wv; t < tiles; t += gridDim.x * 4) {
        int base = t << 4;
        int arow = base + c16;
        half8 af0, af1;
        if (arow < N) {
            if (IN_HALF) {
                const __half* xh = (const __half*)xin;
                af0 = *(const half8*)(xh + (size_t)arow * 64 + kg * 8);
                af1 = *(const half8*)(xh + (size_t)arow * 64 + 32 + kg * 8);
            } else {
                const float* xf = (const float*)xin;
                float4 u0 = *(const float4*)(xf + (size_t)arow * 64 + kg * 8);
                float4 u1 = *(const float4*)(xf + (size_t)arow * 64 + kg * 8 + 4);
                float4 u2 = *(const float4*)(xf + (size_t)arow * 64 + 32 + kg * 8);
                float4 u3 = *(const float4*)(xf + (size_t)arow * 64 + 32 + kg * 8 + 4);
                af0[0]=(_Float16)u0.x; af0[1]=(_Float16)u0.y; af0[2]=(_Float16)u0.z; af0[3]=(_Float16)u0.w;
                af0[4]=(_Float16)u1.x; af0[5]=(_Float16)u1.y; af0[6]=(_Float16)u1.z; af0[7]=(_Float16)u1.w;
                af1[0]=(_Float16)u2.x; af1[1]=(_Float16)u2.y; af1[2]=(_Float16)u2.z; af1[3]=(_Float16)u2.w;
                af1[4]=(_Float16)u3.x; af1[5]=(_Float16)u3.y; af1[6]=(_Float16)u3.z; af1[7]=(_Float16)u3.w;
            }
        } else {
#pragma unroll
            for (int j = 0; j < 8; ++j) { af0[j] = (_Float16)0.f; af1[j] = (_Float16)0.f; }
        }
#pragma unroll
        for (int ct = 0; ct < 4; ++ct) {
            float4v c = {0.f, 0.f, 0.f, 0.f};
            c = __builtin_amdgcn_mfma_f32_16x16x32_f16(af0, bf[ct][0], c, 0, 0, 0);
            c = __builtin_amdgcn_mfma_f32_16x16x32_f16(af1, bf[ct][1], c, 0, 0, 0);
#pragma unroll
            for (int q = 0; q < 4; ++q) {
                int rr = base + kg * 4 + q;
                if (rr < N) yh[(size_t)rr * 64 + ct * 16 + c16] = __float2half_rn(c[q] * dinv[rr]);
            }
        }
    }
}

// One wave per node. 8 groups x 8 lanes; lane (g,i) loads 16B chunk i of row srcs[e+k*8+g].
// 32 edges in flight per iteration; packed v_pk_add_f16 accumulation (4 VALU per 16B);
// packed shfl-xor reduce; fp32 epilogue (self-loop already in acc, dinv+bias+SiLU).
__global__ __launch_bounds__(256) void k_agg(const int* __restrict__ starts,
                                             const int* __restrict__ srcs,
                                             const __half* __restrict__ yh,
                                             const float* __restrict__ dinv,
                                             const float* __restrict__ b,
                                             __half* __restrict__ xh, int N) {
    int wid = (blockIdx.x * blockDim.x + threadIdx.x) >> 6;
    if (wid >= N) return;
    int lane = threadIdx.x & 63;
    int g = lane >> 3, i = lane & 7;
    const float4* y4 = (const float4*)yh;   // row = 8 float4 chunks
    __half2 acc0, acc1, acc2, acc3;
    acc0 = acc1 = acc2 = acc3 = __half2half2(__ushort_as_half((unsigned short)0));

    if (g == 0) {  // self loop
        float4 raw = y4[(size_t)wid * 8 + i];
        const __half2* h = (const __half2*)&raw;
        acc0 = h[0]; acc1 = h[1]; acc2 = h[2]; acc3 = h[3];
    }
    int s = starts[wid], t = starts[wid + 1];
    for (int e = s; e < t; e += 32) {
        int e0 = e + g, e1 = e + 8 + g, e2 = e + 16 + g, e3 = e + 24 + g;
        if (e0 < t) {
            float4 raw = y4[(size_t)srcs[e0] * 8 + i];
            const __half2* h = (const __half2*)&raw;
            acc0 = __hadd2(acc0, h[0]); acc1 = __hadd2(acc1, h[1]);
            acc2 = __hadd2(acc2, h[2]); acc3 = __hadd2(acc3, h[3]);
        }
        if (e1 < t) {
            float4 raw = y4[(size_t)srcs[e1] * 8 + i];
            const __half2* h = (const __half2*)&raw;
            acc0 = __hadd2(acc0, h[0]); acc1 = __hadd2(acc1, h[1]);
            acc2 = __hadd2(acc2, h[2]); acc3 = __hadd2(acc3, h[3]);
        }
        if (e2 < t) {
            float4 raw = y4[(size_t)srcs[e2] * 8 + i];
            const __half2* h = (const __half2*)&raw;
            acc0 = __hadd2(acc0, h[0]); acc1 = __hadd2(acc1, h[1]);
            acc2 = __hadd2(acc2, h[2]); acc3 = __hadd2(acc3, h[3]);
        }
        if (e3 < t) {
            float4 raw = y4[(size_t)srcs[e3] * 8 + i];
            const __half2* h = (const __half2*)&raw;
            acc0 = __hadd2(acc0, h[0]); acc1 = __hadd2(acc1, h[1]);
            acc2 = __hadd2(acc2, h[2]); acc3 = __hadd2(acc3, h[3]);
        }
    }
#pragma unroll
    for (int off = 8; off <= 32; off <<= 1) {
        int o0 = __shfl_xor(*(int*)&acc0, off);
        int o1 = __shfl_xor(*(int*)&acc1, off);
        int o2 = __shfl_xor(*(int*)&acc2, off);
        int o3 = __shfl_xor(*(int*)&acc3, off);
        acc0 = __hadd2(acc0, *(__half2*)&o0);
        acc1 = __hadd2(acc1, *(__half2*)&o1);
        acc2 = __hadd2(acc2, *(__half2*)&o2);
        acc3 = __hadd2(acc3, *(__half2*)&o3);
    }

    if (g == 0) {
        float d = dinv[wid];
        float4 b0 = ((const float4*)b)[2 * i];
        float4 b1 = ((const float4*)b)[2 * i + 1];
        float bb[8] = {b0.x, b0.y, b0.z, b0.w, b1.x, b1.y, b1.z, b1.w};
        float2 f0 = __half22float2(acc0), f1 = __half22float2(acc1);
        float2 f2 = __half22float2(acc2), f3 = __half22float2(acc3);
        float sums[8] = {f0.x, f0.y, f1.x, f1.y, f2.x, f2.y, f3.x, f3.y};
        float o[8];
#pragma unroll
        for (int f = 0; f < 8; ++f) {
            float v = d * sums[f] + bb[f];
            o[f] = v / (1.f + __expf(-v));
        }
        float4 outv;
        __half2* oh = (__half2*)&outv;
#pragma unroll
        for (int p = 0; p < 4; ++p) oh[p] = __float22half2_rn(make_float2(o[2 * p], o[2 * p + 1]));
        ((float4*)xh)[(size_t)wid * 8 + i] = outv;
    }
}

// One block per graph: binary-search segment, mean-pool (fp32 accum), readout, log_softmax
__global__ void k_pool_readout(const __half2* __restrict__ xh2, const int* __restrict__ batch, int N,
                               const float* __restrict__ Wro, const float* __restrict__ bro,
                               float* __restrict__ out, int C) {
    int g = blockIdx.x;
    int tid = threadIdx.x, wave = tid >> 6, lane = tid & 63;
    int grp = lane >> 5, i = lane & 31;
    __shared__ float part[4][64];
    __shared__ float pooled[64];
    __shared__ float logits[32];
    int lo = 0, hb = N;
    while (lo < hb) { int m = (lo + hb) >> 1; if (batch[m] < g) lo = m + 1; else hb = m; }
    int lo2 = lo, hi2 = N;
    while (lo2 < hi2) { int m = (lo2 + hi2) >> 1; if (batch[m] < g + 1) lo2 = m + 1; else hi2 = m; }
    int hi = lo2;
    float ax = 0.f, ay = 0.f;
    for (int r = lo + wave * 2 + grp; r < hi; r += 8) {
        float2 v = __half22float2(xh2[(size_t)r * 32 + i]);
        ax += v.x; ay += v.y;
    }
    ax += __shfl_xor(ax, 32);
    ay += __shfl_xor(ay, 32);
    if (grp == 0) { part[wave][2 * i] = ax; part[wave][2 * i + 1] = ay; }
    __syncthreads();
    if (tid < 64) {
        float cntf = fmaxf((float)(hi - lo), 1.0f);
        pooled[tid] = (part[0][tid] + part[1][tid] + part[2][tid] + part[3][tid]) / cntf;
    }
    __syncthreads();
    if (tid < C) {
        float a = bro[tid];
        for (int k = 0; k < 64; ++k) a += pooled[k] * Wro[k * C + tid];
        logits[tid] = fmaxf(a, 0.f);
    }
    __syncthreads();
    if (tid == 0) {
        float m = -1e30f;
        for (int c = 0; c < C; ++c) m = fmaxf(m, logits[c]);
        float sum = 0.f;
        for (int c = 0; c < C; ++c) sum += __expf(logits[c] - m);
        float lse = m + __logf(sum);
        for (int c = 0; c < C; ++c) out[g * C + c] = logits[c] - lse;
    }
}

static inline size_t align256(size_t v) { return (v + 255) & ~(size_t)255; }

extern "C" void kernel_launch(void* const* d_in, const int* in_sizes, int n_in,
                              void* d_out, int out_size, void* d_ws, size_t ws_size,
                              hipStream_t stream) {
    const float* x    = (const float*)d_in[0];
    const int*   ei   = (const int*)d_in[1];
    const int*   batch= (const int*)d_in[2];
    const float* W[3] = {(const float*)d_in[4], (const float*)d_in[6], (const float*)d_in[8]};
    const float* b[3] = {(const float*)d_in[5], (const float*)d_in[7], (const float*)d_in[9]};
    const float* Wro  = (const float*)d_in[10];
    const float* bro  = (const float*)d_in[11];

    int N = in_sizes[2];
    int E = in_sizes[1] / 2;
    int C = in_sizes[10] / 64;
    int G = out_size / C;

    const int* row = ei;          // sources
    const int* col = ei + E;      // targets

    int NB = (N + BNODES - 1) >> BSH;      // target buckets (<=1024)
    int Ec = (E + CH - 1) / CH;            // edges per chunk

    char* ws = (char*)d_ws;
    size_t off = 0;
    float* dinv    = (float*)(ws + off);        off = align256(off + (size_t)N * 4);
    int*   histG   = (int*)(ws + off);          off = align256(off + (size_t)CH * NB * 4);
    int*   btot    = (int*)(ws + off);          off = align256(off + (size_t)NB * 4);
    int*   bstart  = (int*)(ws + off);          off = align256(off + (size_t)(NB + 1) * 4);
    unsigned int* edges = (unsigned int*)(ws + off); off = align256(off + (size_t)E * 4);
    int*   srcs    = (int*)(ws + off);          off = align256(off + (size_t)E * 4);
    int*   starts  = (int*)(ws + off);          off = align256(off + (size_t)(N + 1) * 4);
    __half* yh     = (__half*)(ws + off);       off = align256(off + (size_t)N * 64 * 2);
    __half* xh     = (__half*)(ws + off);       off = align256(off + (size_t)N * 64 * 2);

    k_hist<<<CH, 256, 0, stream>>>(col, E, Ec, NB, histG);
    k_scanb<<<NB, 64, 0, stream>>>(histG, NB, btot);
    k_scant<<<1, 1024, 0, stream>>>(btot, NB, E, bstart);
    k_scatter<<<CH, 256, 0, stream>>>(col, row, E, Ec, NB, histG, bstart, edges);
    k_sort2<<<NB, 256, 0, stream>>>(edges, bstart, N, E, NB, srcs, starts, dinv);

    int aggB = (N + 3) / 4;     // 4 waves (nodes) per 256-thread block
    int gemmB = 1568;           // ~1 16-row tile per wave

    k_gemm<0><<<gemmB, 256, 0, stream>>>(x, W[0], dinv, yh, N);
    k_agg<<<aggB, 256, 0, stream>>>(starts, srcs, yh, dinv, b[0], xh, N);
    k_gemm<1><<<gemmB, 256, 0, stream>>>(xh, W[1], dinv, yh, N);
    k_agg<<<aggB, 256, 0, stream>>>(starts, srcs, yh, dinv, b[1], xh, N);
    k_gemm<1><<<gemmB, 256, 0, stream>>>(xh, W[2], dinv, yh, N);
    k_agg<<<aggB, 256, 0, stream>>>(starts, srcs, yh, dinv, b[2], xh, N);

    k_pool_readout<<<G, 256, 0, stream>>>((const __half2*)xh, batch, N, Wro, bro, (float*)d_out, C);
}

// Round 8
// 249.763 us; speedup vs baseline: 8.8455x; 1.2166x over previous
//
#include <hip/hip_runtime.h>
#include <hip/hip_fp16.h>

// GCN: 3x (x = silu(Dinv A Dinv (x W) + b)) -> mean-pool -> relu(pooled@Wro+bro) -> log_softmax
// y = (x@W)*dinv[row] fp16; out[c] = dinv[c]*(sum_{r->c} y[r] + y[c]) + b; x' = silu(out) fp16.
// CSR built once via atomic-free two-level counting sort (bucket hist/scan/scatter + in-bucket sort).
// Aggregation: 8 nodes per wave (8 lanes/node), per-group CSR loop, packed fp16 adds, no reduction.

#define CH 128          // edge chunks
#define BSH 7           // log2(nodes per bucket)
#define BNODES 128

typedef _Float16 half8 __attribute__((ext_vector_type(8)));
typedef float float4v __attribute__((ext_vector_type(4)));

// Phase 1: per-chunk histogram over target buckets (LDS atomics only)
__global__ __launch_bounds__(256) void k_hist(const int* __restrict__ col, int E, int Ec, int NB,
                                              int* __restrict__ histG) {
    __shared__ int h[1024];
    int c = blockIdx.x, tid = threadIdx.x;
    for (int i = tid; i < NB; i += 256) h[i] = 0;
    __syncthreads();
    int lo = c * Ec, hi = min(E, lo + Ec);
    for (int e = lo + tid; e < hi; e += 256) atomicAdd(&h[col[e] >> BSH], 1);
    __syncthreads();
    for (int i = tid; i < NB; i += 256) histG[c * NB + i] = h[i];
}

// Phase 2a: per bucket, exclusive scan across CH=128 chunks (one wave per bucket)
__global__ void k_scanb(int* __restrict__ histG, int NB, int* __restrict__ btot) {
    int b = blockIdx.x;
    int l = threadIdx.x;  // 0..63
    int v0 = histG[l * NB + b];
    int v1 = histG[(64 + l) * NB + b];
    int p0 = v0, p1 = v1;
    for (int off = 1; off < 64; off <<= 1) {
        int t0 = __shfl_up(p0, off);
        int t1 = __shfl_up(p1, off);
        if (l >= off) { p0 += t0; p1 += t1; }
    }
    int A = __shfl(p0, 63);          // total of chunks 0..63
    int T = A + __shfl(p1, 63);      // bucket total
    histG[l * NB + b] = p0 - v0;             // exclusive offset for chunk l
    histG[(64 + l) * NB + b] = A + p1 - v1;  // exclusive offset for chunk 64+l
    if (l == 0) btot[b] = T;
}

// Phase 2b: exclusive scan of bucket totals -> bucket start offsets
__global__ void k_scant(const int* __restrict__ btot, int NB, int E, int* __restrict__ bstart) {
    __shared__ int s[1024];
    int tid = threadIdx.x;
    int v = (tid < NB) ? btot[tid] : 0;
    s[tid] = v;
    __syncthreads();
    for (int off = 1; off < 1024; off <<= 1) {
        int t = (tid >= off) ? s[tid - off] : 0;
        __syncthreads();
        s[tid] += t;
        __syncthreads();
    }
    if (tid < NB) bstart[tid] = s[tid] - v;
    if (tid == 0) bstart[NB] = E;
}

// Phase 3: scatter edges into bucket-grouped order. LDS cursors, no global atomics.
// Packed edge: bits 0..24 = source row, bits 25..31 = target's low 7 bits.
__global__ __launch_bounds__(256) void k_scatter(const int* __restrict__ col, const int* __restrict__ row,
                                                 int E, int Ec, int NB,
                                                 const int* __restrict__ histG,
                                                 const int* __restrict__ bstart,
                                                 unsigned int* __restrict__ edges) {
    __shared__ int cur[1024];
    int c = blockIdx.x, tid = threadIdx.x;
    for (int i = tid; i < NB; i += 256) cur[i] = bstart[i] + histG[c * NB + i];
    __syncthreads();
    int lo = c * Ec, hi = min(E, lo + Ec);
    for (int e = lo + tid; e < hi; e += 256) {
        int cc = col[e];
        int b = cc >> BSH;
        int pos = atomicAdd(&cur[b], 1);   // LDS atomic
        edges[pos] = (unsigned int)row[e] | ((unsigned int)(cc & (BNODES - 1)) << 25);
    }
}

// Phase 4: within each bucket, counting-sort edges by local node -> per-node CSR + dinv.
// srcs stored PRE-SCALED (*8) = float4-chunk index of the source row.
__global__ __launch_bounds__(256) void k_sort2(const unsigned int* __restrict__ edges,
                                               const int* __restrict__ bstart, int N, int E, int NB,
                                               int* __restrict__ srcs, int* __restrict__ starts,
                                               float* __restrict__ dinv) {
    __shared__ int cnt[BNODES];
    __shared__ int cur[BNODES];
    int b = blockIdx.x, tid = threadIdx.x;
    if (tid < BNODES) cnt[tid] = 0;
    __syncthreads();
    int lo = bstart[b], hi = bstart[b + 1];
    for (int e = lo + tid; e < hi; e += 256) atomicAdd(&cnt[edges[e] >> 25], 1);
    __syncthreads();
    if (tid < 64) {   // wave 0: exclusive scan of cnt[128], 2 elems/lane
        int v0 = cnt[tid], v1 = cnt[64 + tid];
        int p0 = v0, p1 = v1;
        for (int off = 1; off < 64; off <<= 1) {
            int t0 = __shfl_up(p0, off);
            int t1 = __shfl_up(p1, off);
            if (tid >= off) { p0 += t0; p1 += t1; }
        }
        int A = __shfl(p0, 63);
        cur[tid] = lo + p0 - v0;
        cur[64 + tid] = lo + A + p1 - v1;
    }
    __syncthreads();
    int ng = b * BNODES + tid;
    if (tid < BNODES && ng < N) {
        starts[ng] = cur[tid];
        dinv[ng] = rsqrtf((float)cnt[tid] + 1.0f);
    }
    if (b == 0 && tid == 0) starts[N] = E;
    __syncthreads();   // starts must be read out before cursors move
    for (int e = lo + tid; e < hi; e += 256) {
        unsigned int p = edges[e];
        int pos = atomicAdd(&cur[p >> 25], 1);   // LDS atomic
        srcs[pos] = (int)((p & 0x1FFFFFFu) << 3);   // pre-scaled: row * 8
    }
}

// MFMA GEMM: yh[r] = fp16((x[r] @ W) * dinv[r]).
template <int IN_HALF>
__global__ __launch_bounds__(256) void k_gemm(const void* __restrict__ xin,
                                              const float* __restrict__ W,
                                              const float* __restrict__ dinv,
                                              __half* __restrict__ yh, int N) {
    __shared__ float sW[64 * 64];
    int tid = threadIdx.x;
    for (int k = tid; k < 4096; k += 256) sW[k] = W[k];
    __syncthreads();
    int lane = tid & 63, wv = tid >> 6;
    int c16 = lane & 15, kg = lane >> 4;
    half8 bf[4][2];
#pragma unroll
    for (int ct = 0; ct < 4; ++ct)
#pragma unroll
        for (int ks = 0; ks < 2; ++ks)
#pragma unroll
            for (int j = 0; j < 8; ++j)
                bf[ct][ks][j] = (_Float16)sW[(ks * 32 + kg * 8 + j) * 64 + ct * 16 + c16];

    int tiles = (N + 15) >> 4;
    for (int t = blockIdx.x * 4 + wv; t < tiles; t += gridDim.x * 4) {
        int base = t << 4;
        int arow = base + c16;
        half8 af0, af1;
        if (arow < N) {
            if (IN_HALF) {
                const __half* xh = (const __half*)xin;
                af0 = *(const half8*)(xh + (size_t)arow * 64 + kg * 8);
                af1 = *(const half8*)(xh + (size_t)arow * 64 + 32 + kg * 8);
            } else {
                const float* xf = (const float*)xin;
                float4 u0 = *(const float4*)(xf + (size_t)arow * 64 + kg * 8);
                float4 u1 = *(const float4*)(xf + (size_t)arow * 64 + kg * 8 + 4);
                float4 u2 = *(const float4*)(xf + (size_t)arow * 64 + 32 + kg * 8);
                float4 u3 = *(const float4*)(xf + (size_t)arow * 64 + 32 + kg * 8 + 4);
                af0[0]=(_Float16)u0.x; af0[1]=(_Float16)u0.y; af0[2]=(_Float16)u0.z; af0[3]=(_Float16)u0.w;
                af0[4]=(_Float16)u1.x; af0[5]=(_Float16)u1.y; af0[6]=(_Float16)u1.z; af0[7]=(_Float16)u1.w;
                af1[0]=(_Float16)u2.x; af1[1]=(_Float16)u2.y; af1[2]=(_Float16)u2.z; af1[3]=(_Float16)u2.w;
                af1[4]=(_Float16)u3.x; af1[5]=(_Float16)u3.y; af1[6]=(_Float16)u3.z; af1[7]=(_Float16)u3.w;
            }
        } else {
#pragma unroll
            for (int j = 0; j < 8; ++j) { af0[j] = (_Float16)0.f; af1[j] = (_Float16)0.f; }
        }
#pragma unroll
        for (int ct = 0; ct < 4; ++ct) {
            float4v c = {0.f, 0.f, 0.f, 0.f};
            c = __builtin_amdgcn_mfma_f32_16x16x32_f16(af0, bf[ct][0], c, 0, 0, 0);
            c = __builtin_amdgcn_mfma_f32_16x16x32_f16(af1, bf[ct][1], c, 0, 0, 0);
#pragma unroll
            for (int q = 0; q < 4; ++q) {
                int rr = base + kg * 4 + q;
                if (rr < N) yh[(size_t)rr * 64 + ct * 16 + c16] = __float2half_rn(c[q] * dinv[rr]);
            }
        }
    }
}

// 8 nodes per wave: group g (8 lanes) owns node wave*8+g entirely; lane i owns 16B chunk i.
// Per-group loop over own CSR segment, packed fp16 adds, NO cross-lane reduction.
// Epilogue: all 64 lanes active (8 nodes at once): dinv + bias + SiLU, fp32.
__global__ __launch_bounds__(256) void k_agg(const int* __restrict__ starts,
                                             const int* __restrict__ srcs,   // pre-scaled *8
                                             const __half* __restrict__ yh,
                                             const float* __restrict__ dinv,
                                             const float* __restrict__ b,
                                             __half* __restrict__ xh, int N) {
    int wv = (blockIdx.x * blockDim.x + threadIdx.x) >> 6;
    int lane = threadIdx.x & 63;
    int g = lane >> 3, i = lane & 7;
    int node = wv * 8 + g;
    bool valid = node < N;
    const float4* y4 = (const float4*)yh;   // row = 8 float4 chunks
    __half2 a0, a1, a2, a3;
    a0 = a1 = a2 = a3 = __half2half2(__ushort_as_half((unsigned short)0));
    int s = 0, t = 0;
    if (valid) {
        s = starts[node]; t = starts[node + 1];
        float4 raw = y4[(size_t)node * 8 + i];   // self loop
        const __half2* h = (const __half2*)&raw;
        a0 = h[0]; a1 = h[1]; a2 = h[2]; a3 = h[3];
    }
    int e = s;
    for (; e + 1 < t; e += 2) {
        int s0 = srcs[e], s1 = srcs[e + 1];
        float4 r0 = y4[(size_t)s0 + i];
        float4 r1 = y4[(size_t)s1 + i];
        const __half2* h0 = (const __half2*)&r0;
        const __half2* h1 = (const __half2*)&r1;
        a0 = __hadd2(__hadd2(a0, h0[0]), h1[0]);
        a1 = __hadd2(__hadd2(a1, h0[1]), h1[1]);
        a2 = __hadd2(__hadd2(a2, h0[2]), h1[2]);
        a3 = __hadd2(__hadd2(a3, h0[3]), h1[3]);
    }
    if (e < t) {
        int s0 = srcs[e];
        float4 r0 = y4[(size_t)s0 + i];
        const __half2* h0 = (const __half2*)&r0;
        a0 = __hadd2(a0, h0[0]); a1 = __hadd2(a1, h0[1]);
        a2 = __hadd2(a2, h0[2]); a3 = __hadd2(a3, h0[3]);
    }
    if (valid) {
        float d = dinv[node];
        float4 b0 = ((const float4*)b)[2 * i];
        float4 b1 = ((const float4*)b)[2 * i + 1];
        float bb[8] = {b0.x, b0.y, b0.z, b0.w, b1.x, b1.y, b1.z, b1.w};
        float2 f0 = __half22float2(a0), f1 = __half22float2(a1);
        float2 f2 = __half22float2(a2), f3 = __half22float2(a3);
        float sums[8] = {f0.x, f0.y, f1.x, f1.y, f2.x, f2.y, f3.x, f3.y};
        float o[8];
#pragma unroll
        for (int f = 0; f < 8; ++f) {
            float v = d * sums[f] + bb[f];
            o[f] = v / (1.f + __expf(-v));
        }
        float4 outv;
        __half2* oh = (__half2*)&outv;
#pragma unroll
        for (int p = 0; p < 4; ++p) oh[p] = __float22half2_rn(make_float2(o[2 * p], o[2 * p + 1]));
        ((float4*)xh)[(size_t)node * 8 + i] = outv;
    }
}

// One block per graph: binary-search segment, mean-pool (fp32 accum), readout, log_softmax
__global__ void k_pool_readout(const __half2* __restrict__ xh2, const int* __restrict__ batch, int N,
                               const float* __restrict__ Wro, const float* __restrict__ bro,
                               float* __restrict__ out, int C) {
    int g = blockIdx.x;
    int tid = threadIdx.x, wave = tid >> 6, lane = tid & 63;
    int grp = lane >> 5, i = lane & 31;
    __shared__ float part[4][64];
    __shared__ float pooled[64];
    __shared__ float logits[32];
    int lo = 0, hb = N;
    while (lo < hb) { int m = (lo + hb) >> 1; if (batch[m] < g) lo = m + 1; else hb = m; }
    int lo2 = lo, hi2 = N;
    while (lo2 < hi2) { int m = (lo2 + hi2) >> 1; if (batch[m] < g + 1) lo2 = m + 1; else hi2 = m; }
    int hi = lo2;
    float ax = 0.f, ay = 0.f;
    for (int r = lo + wave * 2 + grp; r < hi; r += 8) {
        float2 v = __half22float2(xh2[(size_t)r * 32 + i]);
        ax += v.x; ay += v.y;
    }
    ax += __shfl_xor(ax, 32);
    ay += __shfl_xor(ay, 32);
    if (grp == 0) { part[wave][2 * i] = ax; part[wave][2 * i + 1] = ay; }
    __syncthreads();
    if (tid < 64) {
        float cntf = fmaxf((float)(hi - lo), 1.0f);
        pooled[tid] = (part[0][tid] + part[1][tid] + part[2][tid] + part[3][tid]) / cntf;
    }
    __syncthreads();
    if (tid < C) {
        float a = bro[tid];
        for (int k = 0; k < 64; ++k) a += pooled[k] * Wro[k * C + tid];
        logits[tid] = fmaxf(a, 0.f);
    }
    __syncthreads();
    if (tid == 0) {
        float m = -1e30f;
        for (int c = 0; c < C; ++c) m = fmaxf(m, logits[c]);
        float sum = 0.f;
        for (int c = 0; c < C; ++c) sum += __expf(logits[c] - m);
        float lse = m + __logf(sum);
        for (int c = 0; c < C; ++c) out[g * C + c] = logits[c] - lse;
    }
}

static inline size_t align256(size_t v) { return (v + 255) & ~(size_t)255; }

extern "C" void kernel_launch(void* const* d_in, const int* in_sizes, int n_in,
                              void* d_out, int out_size, void* d_ws, size_t ws_size,
                              hipStream_t stream) {
    const float* x    = (const float*)d_in[0];
    const int*   ei   = (const int*)d_in[1];
    const int*   batch= (const int*)d_in[2];
    const float* W[3] = {(const float*)d_in[4], (const float*)d_in[6], (const float*)d_in[8]};
    const float* b[3] = {(const float*)d_in[5], (const float*)d_in[7], (const float*)d_in[9]};
    const float* Wro  = (const float*)d_in[10];
    const float* bro  = (const float*)d_in[11];

    int N = in_sizes[2];
    int E = in_sizes[1] / 2;
    int C = in_sizes[10] / 64;
    int G = out_size / C;

    const int* row = ei;          // sources
    const int* col = ei + E;      // targets

    int NB = (N + BNODES - 1) >> BSH;      // target buckets (<=1024)
    int Ec = (E + CH - 1) / CH;            // edges per chunk

    char* ws = (char*)d_ws;
    size_t off = 0;
    float* dinv    = (float*)(ws + off);        off = align256(off + (size_t)N * 4);
    int*   histG   = (int*)(ws + off);          off = align256(off + (size_t)CH * NB * 4);
    int*   btot    = (int*)(ws + off);          off = align256(off + (size_t)NB * 4);
    int*   bstart  = (int*)(ws + off);          off = align256(off + (size_t)(NB + 1) * 4);
    unsigned int* edges = (unsigned int*)(ws + off); off = align256(off + (size_t)E * 4);
    int*   srcs    = (int*)(ws + off);          off = align256(off + (size_t)E * 4);
    int*   starts  = (int*)(ws + off);          off = align256(off + (size_t)(N + 1) * 4);
    __half* yh     = (__half*)(ws + off);       off = align256(off + (size_t)N * 64 * 2);
    __half* xh     = (__half*)(ws + off);       off = align256(off + (size_t)N * 64 * 2);

    k_hist<<<CH, 256, 0, stream>>>(col, E, Ec, NB, histG);
    k_scanb<<<NB, 64, 0, stream>>>(histG, NB, btot);
    k_scant<<<1, 1024, 0, stream>>>(btot, NB, E, bstart);
    k_scatter<<<CH, 256, 0, stream>>>(col, row, E, Ec, NB, histG, bstart, edges);
    k_sort2<<<NB, 256, 0, stream>>>(edges, bstart, N, E, NB, srcs, starts, dinv);

    int aggB = (N + 31) / 32;   // 8 nodes/wave, 4 waves/block = 32 nodes/block
    int gemmB = 1568;           // ~1 16-row tile per wave

    k_gemm<0><<<gemmB, 256, 0, stream>>>(x, W[0], dinv, yh, N);
    k_agg<<<aggB, 256, 0, stream>>>(starts, srcs, yh, dinv, b[0], xh, N);
    k_gemm<1><<<gemmB, 256, 0, stream>>>(xh, W[1], dinv, yh, N);
    k_agg<<<aggB, 256, 0, stream>>>(starts, srcs, yh, dinv, b[1], xh, N);
    k_gemm<1><<<gemmB, 256, 0, stream>>>(xh, W[2], dinv, yh, N);
    k_agg<<<aggB, 256, 0, stream>>>(starts, srcs, yh, dinv, b[2], xh, N);

    k_pool_readout<<<G, 256, 0, stream>>>((const __half2*)xh, batch, N, Wro, bro, (float*)d_out, C);
}

// Round 9
// 226.441 us; speedup vs baseline: 9.7565x; 1.1030x over previous
//
#include <hip/hip_runtime.h>
#include <hip/hip_fp16.h>

// GCN: 3x (x = silu(Dinv A Dinv (x W) + b)) -> mean-pool -> relu(pooled@Wro+bro) -> log_softmax
// y = (x@W)*dinv[row] fp16; out[c] = dinv[c]*(sum_{r->c} y[r] + y[c]) + b; x' = silu(out) fp16.
// CSR built once via atomic-free two-level counting sort (bucket hist/scan/scatter + in-bucket sort).
// Aggregation: 8 nodes per wave (8 lanes/node), per-group CSR loop, packed fp16 adds, no reduction.

#define CH 256          // edge chunks
#define BSH 7           // log2(nodes per bucket)
#define BNODES 128

typedef _Float16 half8 __attribute__((ext_vector_type(8)));
typedef float float4v __attribute__((ext_vector_type(4)));

// Phase 1: per-chunk histogram over target buckets (LDS atomics only)
__global__ __launch_bounds__(256) void k_hist(const int* __restrict__ col, int E, int Ec, int NB,
                                              int* __restrict__ histG) {
    __shared__ int h[1024];
    int c = blockIdx.x, tid = threadIdx.x;
    for (int i = tid; i < NB; i += 256) h[i] = 0;
    __syncthreads();
    int lo = c * Ec, hi = min(E, lo + Ec);
    for (int e = lo + tid; e < hi; e += 256) atomicAdd(&h[col[e] >> BSH], 1);
    __syncthreads();
    for (int i = tid; i < NB; i += 256) histG[c * NB + i] = h[i];
}

// Phase 2a: per bucket, exclusive scan across CH=256 chunks (one wave per bucket, 4 chunks/lane)
__global__ void k_scanb(int* __restrict__ histG, int NB, int* __restrict__ btot) {
    int b = blockIdx.x;
    int l = threadIdx.x;  // 0..63
    int v[4], p[4];
#pragma unroll
    for (int k = 0; k < 4; ++k) { v[k] = histG[(k * 64 + l) * NB + b]; p[k] = v[k]; }
    for (int off = 1; off < 64; off <<= 1) {
#pragma unroll
        for (int k = 0; k < 4; ++k) {
            int t = __shfl_up(p[k], off);
            if (l >= off) p[k] += t;
        }
    }
    int acc = 0;
#pragma unroll
    for (int k = 0; k < 4; ++k) {
        int tot = __shfl(p[k], 63);
        histG[(k * 64 + l) * NB + b] = acc + p[k] - v[k];
        acc += tot;
    }
    if (l == 0) btot[b] = acc;
}

// Phase 2b: exclusive scan of bucket totals -> bucket start offsets
__global__ void k_scant(const int* __restrict__ btot, int NB, int E, int* __restrict__ bstart) {
    __shared__ int s[1024];
    int tid = threadIdx.x;
    int v = (tid < NB) ? btot[tid] : 0;
    s[tid] = v;
    __syncthreads();
    for (int off = 1; off < 1024; off <<= 1) {
        int t = (tid >= off) ? s[tid - off] : 0;
        __syncthreads();
        s[tid] += t;
        __syncthreads();
    }
    if (tid < NB) bstart[tid] = s[tid] - v;
    if (tid == 0) bstart[NB] = E;
}

// Phase 3: scatter edges into bucket-grouped order. LDS cursors, no global atomics.
// 1024 threads/block for latency hiding. Packed edge: bits 0..24 src, bits 25..31 tgt low 7.
__global__ __launch_bounds__(1024) void k_scatter(const int* __restrict__ col, const int* __restrict__ row,
                                                  int E, int Ec, int NB,
                                                  const int* __restrict__ histG,
                                                  const int* __restrict__ bstart,
                                                  unsigned int* __restrict__ edges) {
    __shared__ int cur[1024];
    int c = blockIdx.x, tid = threadIdx.x;
    for (int i = tid; i < NB; i += 1024) cur[i] = bstart[i] + histG[c * NB + i];
    __syncthreads();
    int lo = c * Ec, hi = min(E, lo + Ec);
    for (int e = lo + tid; e < hi; e += 1024) {
        int cc = col[e];
        int b = cc >> BSH;
        int pos = atomicAdd(&cur[b], 1);   // LDS atomic
        edges[pos] = (unsigned int)row[e] | ((unsigned int)(cc & (BNODES - 1)) << 25);
    }
}

// Phase 4: within each bucket, counting-sort edges by local node -> per-node CSR + dinv.
// srcs stored PRE-SCALED (*8) = float4-chunk index of the source row.
__global__ __launch_bounds__(512) void k_sort2(const unsigned int* __restrict__ edges,
                                               const int* __restrict__ bstart, int N, int E, int NB,
                                               int* __restrict__ srcs, int* __restrict__ starts,
                                               float* __restrict__ dinv) {
    __shared__ int cnt[BNODES];
    __shared__ int cur[BNODES];
    int b = blockIdx.x, tid = threadIdx.x;
    if (tid < BNODES) cnt[tid] = 0;
    __syncthreads();
    int lo = bstart[b], hi = bstart[b + 1];
    for (int e = lo + tid; e < hi; e += 512) atomicAdd(&cnt[edges[e] >> 25], 1);
    __syncthreads();
    if (tid < 64) {   // wave 0: exclusive scan of cnt[128], 2 elems/lane
        int v0 = cnt[tid], v1 = cnt[64 + tid];
        int p0 = v0, p1 = v1;
        for (int off = 1; off < 64; off <<= 1) {
            int t0 = __shfl_up(p0, off);
            int t1 = __shfl_up(p1, off);
            if (tid >= off) { p0 += t0; p1 += t1; }
        }
        int A = __shfl(p0, 63);
        cur[tid] = lo + p0 - v0;
        cur[64 + tid] = lo + A + p1 - v1;
    }
    __syncthreads();
    int ng = b * BNODES + tid;
    if (tid < BNODES && ng < N) {
        starts[ng] = cur[tid];
        dinv[ng] = rsqrtf((float)cnt[tid] + 1.0f);
    }
    if (b == 0 && tid == 0) starts[N] = E;
    __syncthreads();   // starts must be read out before cursors move
    for (int e = lo + tid; e < hi; e += 512) {
        unsigned int p = edges[e];
        int pos = atomicAdd(&cur[p >> 25], 1);   // LDS atomic
        srcs[pos] = (int)((p & 0x1FFFFFFu) << 3);   // pre-scaled: row * 8
    }
}

// MFMA GEMM: yh[r] = fp16((x[r] @ W) * dinv[r]).
template <int IN_HALF>
__global__ __launch_bounds__(256) void k_gemm(const void* __restrict__ xin,
                                              const float* __restrict__ W,
                                              const float* __restrict__ dinv,
                                              __half* __restrict__ yh, int N) {
    __shared__ float sW[64 * 64];
    int tid = threadIdx.x;
    for (int k = tid; k < 4096; k += 256) sW[k] = W[k];
    __syncthreads();
    int lane = tid & 63, wv = tid >> 6;
    int c16 = lane & 15, kg = lane >> 4;
    half8 bf[4][2];
#pragma unroll
    for (int ct = 0; ct < 4; ++ct)
#pragma unroll
        for (int ks = 0; ks < 2; ++ks)
#pragma unroll
            for (int j = 0; j < 8; ++j)
                bf[ct][ks][j] = (_Float16)sW[(ks * 32 + kg * 8 + j) * 64 + ct * 16 + c16];

    int tiles = (N + 15) >> 4;
    for (int t = blockIdx.x * 4 + wv; t < tiles; t += gridDim.x * 4) {
        int base = t << 4;
        int arow = base + c16;
        half8 af0, af1;
        if (arow < N) {
            if (IN_HALF) {
                const __half* xh = (const __half*)xin;
                af0 = *(const half8*)(xh + (size_t)arow * 64 + kg * 8);
                af1 = *(const half8*)(xh + (size_t)arow * 64 + 32 + kg * 8);
            } else {
                const float* xf = (const float*)xin;
                float4 u0 = *(const float4*)(xf + (size_t)arow * 64 + kg * 8);
                float4 u1 = *(const float4*)(xf + (size_t)arow * 64 + kg * 8 + 4);
                float4 u2 = *(const float4*)(xf + (size_t)arow * 64 + 32 + kg * 8);
                float4 u3 = *(const float4*)(xf + (size_t)arow * 64 + 32 + kg * 8 + 4);
                af0[0]=(_Float16)u0.x; af0[1]=(_Float16)u0.y; af0[2]=(_Float16)u0.z; af0[3]=(_Float16)u0.w;
                af0[4]=(_Float16)u1.x; af0[5]=(_Float16)u1.y; af0[6]=(_Float16)u1.z; af0[7]=(_Float16)u1.w;
                af1[0]=(_Float16)u2.x; af1[1]=(_Float16)u2.y; af1[2]=(_Float16)u2.z; af1[3]=(_Float16)u2.w;
                af1[4]=(_Float16)u3.x; af1[5]=(_Float16)u3.y; af1[6]=(_Float16)u3.z; af1[7]=(_Float16)u3.w;
            }
        } else {
#pragma unroll
            for (int j = 0; j < 8; ++j) { af0[j] = (_Float16)0.f; af1[j] = (_Float16)0.f; }
        }
#pragma unroll
        for (int ct = 0; ct < 4; ++ct) {
            float4v c = {0.f, 0.f, 0.f, 0.f};
            c = __builtin_amdgcn_mfma_f32_16x16x32_f16(af0, bf[ct][0], c, 0, 0, 0);
            c = __builtin_amdgcn_mfma_f32_16x16x32_f16(af1, bf[ct][1], c, 0, 0, 0);
#pragma unroll
            for (int q = 0; q < 4; ++q) {
                int rr = base + kg * 4 + q;
                if (rr < N) yh[(size_t)rr * 64 + ct * 16 + c16] = __float2half_rn(c[q] * dinv[rr]);
            }
        }
    }
}

// 8 nodes per wave: group g (8 lanes) owns node wave*8+g entirely; lane i owns 16B chunk i.
// Per-group loop over own CSR segment (4-edge unroll), packed fp16 adds, NO cross-lane reduction.
__global__ __launch_bounds__(256) void k_agg(const int* __restrict__ starts,
                                             const int* __restrict__ srcs,   // pre-scaled *8
                                             const __half* __restrict__ yh,
                                             const float* __restrict__ dinv,
                                             const float* __restrict__ b,
                                             __half* __restrict__ xh, int N) {
    int wv = (blockIdx.x * blockDim.x + threadIdx.x) >> 6;
    int lane = threadIdx.x & 63;
    int g = lane >> 3, i = lane & 7;
    int node = wv * 8 + g;
    bool valid = node < N;
    const float4* y4 = (const float4*)yh;   // row = 8 float4 chunks
    __half2 a0, a1, a2, a3;
    a0 = a1 = a2 = a3 = __half2half2(__ushort_as_half((unsigned short)0));
    int s = 0, t = 0;
    if (valid) {
        s = starts[node]; t = starts[node + 1];
        float4 raw = y4[(size_t)node * 8 + i];   // self loop
        const __half2* h = (const __half2*)&raw;
        a0 = h[0]; a1 = h[1]; a2 = h[2]; a3 = h[3];
    }
    int e = s;
    for (; e + 3 < t; e += 4) {
        int s0 = srcs[e], s1 = srcs[e + 1], s2 = srcs[e + 2], s3 = srcs[e + 3];
        float4 r0 = y4[(size_t)s0 + i];
        float4 r1 = y4[(size_t)s1 + i];
        float4 r2 = y4[(size_t)s2 + i];
        float4 r3 = y4[(size_t)s3 + i];
        const __half2* h0 = (const __half2*)&r0;
        const __half2* h1 = (const __half2*)&r1;
        const __half2* h2 = (const __half2*)&r2;
        const __half2* h3 = (const __half2*)&r3;
        a0 = __hadd2(__hadd2(__hadd2(a0, h0[0]), h1[0]), __hadd2(h2[0], h3[0]));
        a1 = __hadd2(__hadd2(__hadd2(a1, h0[1]), h1[1]), __hadd2(h2[1], h3[1]));
        a2 = __hadd2(__hadd2(__hadd2(a2, h0[2]), h1[2]), __hadd2(h2[2], h3[2]));
        a3 = __hadd2(__hadd2(__hadd2(a3, h0[3]), h1[3]), __hadd2(h2[3], h3[3]));
    }
    for (; e < t; ++e) {
        int s0 = srcs[e];
        float4 r0 = y4[(size_t)s0 + i];
        const __half2* h0 = (const __half2*)&r0;
        a0 = __hadd2(a0, h0[0]); a1 = __hadd2(a1, h0[1]);
        a2 = __hadd2(a2, h0[2]); a3 = __hadd2(a3, h0[3]);
    }
    if (valid) {
        float d = dinv[node];
        float4 b0 = ((const float4*)b)[2 * i];
        float4 b1 = ((const float4*)b)[2 * i + 1];
        float bb[8] = {b0.x, b0.y, b0.z, b0.w, b1.x, b1.y, b1.z, b1.w};
        float2 f0 = __half22float2(a0), f1 = __half22float2(a1);
        float2 f2 = __half22float2(a2), f3 = __half22float2(a3);
        float sums[8] = {f0.x, f0.y, f1.x, f1.y, f2.x, f2.y, f3.x, f3.y};
        float o[8];
#pragma unroll
        for (int f = 0; f < 8; ++f) {
            float v = d * sums[f] + bb[f];
            o[f] = v / (1.f + __expf(-v));
        }
        float4 outv;
        __half2* oh = (__half2*)&outv;
#pragma unroll
        for (int p = 0; p < 4; ++p) oh[p] = __float22half2_rn(make_float2(o[2 * p], o[2 * p + 1]));
        ((float4*)xh)[(size_t)node * 8 + i] = outv;
    }
}

// One block per graph: binary-search segment, mean-pool (fp32 accum), readout, log_softmax
__global__ void k_pool_readout(const __half2* __restrict__ xh2, const int* __restrict__ batch, int N,
                               const float* __restrict__ Wro, const float* __restrict__ bro,
                               float* __restrict__ out, int C) {
    int g = blockIdx.x;
    int tid = threadIdx.x, wave = tid >> 6, lane = tid & 63;
    int grp = lane >> 5, i = lane & 31;
    __shared__ float part[4][64];
    __shared__ float pooled[64];
    __shared__ float logits[32];
    int lo = 0, hb = N;
    while (lo < hb) { int m = (lo + hb) >> 1; if (batch[m] < g) lo = m + 1; else hb = m; }
    int lo2 = lo, hi2 = N;
    while (lo2 < hi2) { int m = (lo2 + hi2) >> 1; if (batch[m] < g + 1) lo2 = m + 1; else hi2 = m; }
    int hi = lo2;
    float ax = 0.f, ay = 0.f;
    for (int r = lo + wave * 2 + grp; r < hi; r += 8) {
        float2 v = __half22float2(xh2[(size_t)r * 32 + i]);
        ax += v.x; ay += v.y;
    }
    ax += __shfl_xor(ax, 32);
    ay += __shfl_xor(ay, 32);
    if (grp == 0) { part[wave][2 * i] = ax; part[wave][2 * i + 1] = ay; }
    __syncthreads();
    if (tid < 64) {
        float cntf = fmaxf((float)(hi - lo), 1.0f);
        pooled[tid] = (part[0][tid] + part[1][tid] + part[2][tid] + part[3][tid]) / cntf;
    }
    __syncthreads();
    if (tid < C) {
        float a = bro[tid];
        for (int k = 0; k < 64; ++k) a += pooled[k] * Wro[k * C + tid];
        logits[tid] = fmaxf(a, 0.f);
    }
    __syncthreads();
    if (tid == 0) {
        float m = -1e30f;
        for (int c = 0; c < C; ++c) m = fmaxf(m, logits[c]);
        float sum = 0.f;
        for (int c = 0; c < C; ++c) sum += __expf(logits[c] - m);
        float lse = m + __logf(sum);
        for (int c = 0; c < C; ++c) out[g * C + c] = logits[c] - lse;
    }
}

static inline size_t align256(size_t v) { return (v + 255) & ~(size_t)255; }

extern "C" void kernel_launch(void* const* d_in, const int* in_sizes, int n_in,
                              void* d_out, int out_size, void* d_ws, size_t ws_size,
                              hipStream_t stream) {
    const float* x    = (const float*)d_in[0];
    const int*   ei   = (const int*)d_in[1];
    const int*   batch= (const int*)d_in[2];
    const float* W[3] = {(const float*)d_in[4], (const float*)d_in[6], (const float*)d_in[8]};
    const float* b[3] = {(const float*)d_in[5], (const float*)d_in[7], (const float*)d_in[9]};
    const float* Wro  = (const float*)d_in[10];
    const float* bro  = (const float*)d_in[11];

    int N = in_sizes[2];
    int E = in_sizes[1] / 2;
    int C = in_sizes[10] / 64;
    int G = out_size / C;

    const int* row = ei;          // sources
    const int* col = ei + E;      // targets

    int NB = (N + BNODES - 1) >> BSH;      // target buckets (<=1024)
    int Ec = (E + CH - 1) / CH;            // edges per chunk

    char* ws = (char*)d_ws;
    size_t off = 0;
    float* dinv    = (float*)(ws + off);        off = align256(off + (size_t)N * 4);
    int*   histG   = (int*)(ws + off);          off = align256(off + (size_t)CH * NB * 4);
    int*   btot    = (int*)(ws + off);          off = align256(off + (size_t)NB * 4);
    int*   bstart  = (int*)(ws + off);          off = align256(off + (size_t)(NB + 1) * 4);
    unsigned int* edges = (unsigned int*)(ws + off); off = align256(off + (size_t)E * 4);
    int*   srcs    = (int*)(ws + off);          off = align256(off + (size_t)E * 4);
    int*   starts  = (int*)(ws + off);          off = align256(off + (size_t)(N + 1) * 4);
    __half* yh     = (__half*)(ws + off);       off = align256(off + (size_t)N * 64 * 2);
    __half* xh     = (__half*)(ws + off);       off = align256(off + (size_t)N * 64 * 2);

    k_hist<<<CH, 256, 0, stream>>>(col, E, Ec, NB, histG);
    k_scanb<<<NB, 64, 0, stream>>>(histG, NB, btot);
    k_scant<<<1, 1024, 0, stream>>>(btot, NB, E, bstart);
    k_scatter<<<CH, 1024, 0, stream>>>(col, row, E, Ec, NB, histG, bstart, edges);
    k_sort2<<<NB, 512, 0, stream>>>(edges, bstart, N, E, NB, srcs, starts, dinv);

    int aggB = (N + 31) / 32;   // 8 nodes/wave, 4 waves/block = 32 nodes/block
    int gemmB = 1568;           // ~1 16-row tile per wave

    k_gemm<0><<<gemmB, 256, 0, stream>>>(x, W[0], dinv, yh, N);
    k_agg<<<aggB, 256, 0, stream>>>(starts, srcs, yh, dinv, b[0], xh, N);
    k_gemm<1><<<gemmB, 256, 0, stream>>>(xh, W[1], dinv, yh, N);
    k_agg<<<aggB, 256, 0, stream>>>(starts, srcs, yh, dinv, b[1], xh, N);
    k_gemm<1><<<gemmB, 256, 0, stream>>>(xh, W[2], dinv, yh, N);
    k_agg<<<aggB, 256, 0, stream>>>(starts, srcs, yh, dinv, b[2], xh, N);

    k_pool_readout<<<G, 256, 0, stream>>>((const __half2*)xh, batch, N, Wro, bro, (float*)d_out, C);
}

// Round 10
// 206.737 us; speedup vs baseline: 10.6864x; 1.0953x over previous
//
#include <hip/hip_runtime.h>
#include <hip/hip_fp16.h>

// GCN: 3x (x = silu(Dinv A Dinv (x W) + b)) -> mean-pool -> relu(pooled@Wro+bro) -> log_softmax
// y = (x@W)*dinv[row] fp16; out[c] = dinv[c]*(sum_{r->c} y[r] + y[c]) + b; x' = silu(out) fp16.
// CSR built once via atomic-free two-level counting sort (bucket hist/scan/scatter + in-bucket sort).
// Aggregation: 8 nodes per wave (8 lanes/node), per-group CSR loop, packed fp16 adds, no reduction.
// Pooling: wave-per-slice partial sums (flush-on-graph-change) + tiny per-graph readout.

#define CH 256          // edge chunks
#define BSH 7           // log2(nodes per bucket)
#define BNODES 128

typedef _Float16 half8 __attribute__((ext_vector_type(8)));
typedef float float4v __attribute__((ext_vector_type(4)));

// Phase 1: per-chunk histogram over target buckets (LDS atomics only)
__global__ __launch_bounds__(256) void k_hist(const int* __restrict__ col, int E, int Ec, int NB,
                                              int* __restrict__ histG) {
    __shared__ int h[1024];
    int c = blockIdx.x, tid = threadIdx.x;
    for (int i = tid; i < NB; i += 256) h[i] = 0;
    __syncthreads();
    int lo = c * Ec, hi = min(E, lo + Ec);
    for (int e = lo + tid; e < hi; e += 256) atomicAdd(&h[col[e] >> BSH], 1);
    __syncthreads();
    for (int i = tid; i < NB; i += 256) histG[c * NB + i] = h[i];
}

// Phase 2a: per bucket, exclusive scan across CH=256 chunks (one wave per bucket, 4 chunks/lane)
__global__ void k_scanb(int* __restrict__ histG, int NB, int* __restrict__ btot) {
    int b = blockIdx.x;
    int l = threadIdx.x;  // 0..63
    int v[4], p[4];
#pragma unroll
    for (int k = 0; k < 4; ++k) { v[k] = histG[(k * 64 + l) * NB + b]; p[k] = v[k]; }
    for (int off = 1; off < 64; off <<= 1) {
#pragma unroll
        for (int k = 0; k < 4; ++k) {
            int t = __shfl_up(p[k], off);
            if (l >= off) p[k] += t;
        }
    }
    int acc = 0;
#pragma unroll
    for (int k = 0; k < 4; ++k) {
        int tot = __shfl(p[k], 63);
        histG[(k * 64 + l) * NB + b] = acc + p[k] - v[k];
        acc += tot;
    }
    if (l == 0) btot[b] = acc;
}

// Phase 2b: exclusive scan of bucket totals -> bucket start offsets
__global__ void k_scant(const int* __restrict__ btot, int NB, int E, int* __restrict__ bstart) {
    __shared__ int s[1024];
    int tid = threadIdx.x;
    int v = (tid < NB) ? btot[tid] : 0;
    s[tid] = v;
    __syncthreads();
    for (int off = 1; off < 1024; off <<= 1) {
        int t = (tid >= off) ? s[tid - off] : 0;
        __syncthreads();
        s[tid] += t;
        __syncthreads();
    }
    if (tid < NB) bstart[tid] = s[tid] - v;
    if (tid == 0) bstart[NB] = E;
}

// Phase 3: scatter edges into bucket-grouped order. LDS cursors, no global atomics.
__global__ __launch_bounds__(1024) void k_scatter(const int* __restrict__ col, const int* __restrict__ row,
                                                  int E, int Ec, int NB,
                                                  const int* __restrict__ histG,
                                                  const int* __restrict__ bstart,
                                                  unsigned int* __restrict__ edges) {
    __shared__ int cur[1024];
    int c = blockIdx.x, tid = threadIdx.x;
    for (int i = tid; i < NB; i += 1024) cur[i] = bstart[i] + histG[c * NB + i];
    __syncthreads();
    int lo = c * Ec, hi = min(E, lo + Ec);
    for (int e = lo + tid; e < hi; e += 1024) {
        int cc = col[e];
        int b = cc >> BSH;
        int pos = atomicAdd(&cur[b], 1);   // LDS atomic
        edges[pos] = (unsigned int)row[e] | ((unsigned int)(cc & (BNODES - 1)) << 25);
    }
}

// Phase 4: within each bucket, counting-sort edges by local node -> per-node CSR + dinv.
// srcs stored PRE-SCALED (*8) = float4-chunk index of the source row.
__global__ __launch_bounds__(512) void k_sort2(const unsigned int* __restrict__ edges,
                                               const int* __restrict__ bstart, int N, int E, int NB,
                                               int* __restrict__ srcs, int* __restrict__ starts,
                                               float* __restrict__ dinv) {
    __shared__ int cnt[BNODES];
    __shared__ int cur[BNODES];
    int b = blockIdx.x, tid = threadIdx.x;
    if (tid < BNODES) cnt[tid] = 0;
    __syncthreads();
    int lo = bstart[b], hi = bstart[b + 1];
    for (int e = lo + tid; e < hi; e += 512) atomicAdd(&cnt[edges[e] >> 25], 1);
    __syncthreads();
    if (tid < 64) {   // wave 0: exclusive scan of cnt[128], 2 elems/lane
        int v0 = cnt[tid], v1 = cnt[64 + tid];
        int p0 = v0, p1 = v1;
        for (int off = 1; off < 64; off <<= 1) {
            int t0 = __shfl_up(p0, off);
            int t1 = __shfl_up(p1, off);
            if (tid >= off) { p0 += t0; p1 += t1; }
        }
        int A = __shfl(p0, 63);
        cur[tid] = lo + p0 - v0;
        cur[64 + tid] = lo + A + p1 - v1;
    }
    __syncthreads();
    int ng = b * BNODES + tid;
    if (tid < BNODES && ng < N) {
        starts[ng] = cur[tid];
        dinv[ng] = rsqrtf((float)cnt[tid] + 1.0f);
    }
    if (b == 0 && tid == 0) starts[N] = E;
    __syncthreads();   // starts must be read out before cursors move
    for (int e = lo + tid; e < hi; e += 512) {
        unsigned int p = edges[e];
        int pos = atomicAdd(&cur[p >> 25], 1);   // LDS atomic
        srcs[pos] = (int)((p & 0x1FFFFFFu) << 3);   // pre-scaled: row * 8
    }
}

// MFMA GEMM: yh[r] = fp16((x[r] @ W) * dinv[r]).
template <int IN_HALF>
__global__ __launch_bounds__(256) void k_gemm(const void* __restrict__ xin,
                                              const float* __restrict__ W,
                                              const float* __restrict__ dinv,
                                              __half* __restrict__ yh, int N) {
    __shared__ float sW[64 * 64];
    int tid = threadIdx.x;
    for (int k = tid; k < 4096; k += 256) sW[k] = W[k];
    __syncthreads();
    int lane = tid & 63, wv = tid >> 6;
    int c16 = lane & 15, kg = lane >> 4;
    half8 bf[4][2];
#pragma unroll
    for (int ct = 0; ct < 4; ++ct)
#pragma unroll
        for (int ks = 0; ks < 2; ++ks)
#pragma unroll
            for (int j = 0; j < 8; ++j)
                bf[ct][ks][j] = (_Float16)sW[(ks * 32 + kg * 8 + j) * 64 + ct * 16 + c16];

    int tiles = (N + 15) >> 4;
    for (int t = blockIdx.x * 4 + wv; t < tiles; t += gridDim.x * 4) {
        int base = t << 4;
        int arow = base + c16;
        half8 af0, af1;
        if (arow < N) {
            if (IN_HALF) {
                const __half* xh = (const __half*)xin;
                af0 = *(const half8*)(xh + (size_t)arow * 64 + kg * 8);
                af1 = *(const half8*)(xh + (size_t)arow * 64 + 32 + kg * 8);
            } else {
                const float* xf = (const float*)xin;
                float4 u0 = *(const float4*)(xf + (size_t)arow * 64 + kg * 8);
                float4 u1 = *(const float4*)(xf + (size_t)arow * 64 + kg * 8 + 4);
                float4 u2 = *(const float4*)(xf + (size_t)arow * 64 + 32 + kg * 8);
                float4 u3 = *(const float4*)(xf + (size_t)arow * 64 + 32 + kg * 8 + 4);
                af0[0]=(_Float16)u0.x; af0[1]=(_Float16)u0.y; af0[2]=(_Float16)u0.z; af0[3]=(_Float16)u0.w;
                af0[4]=(_Float16)u1.x; af0[5]=(_Float16)u1.y; af0[6]=(_Float16)u1.z; af0[7]=(_Float16)u1.w;
                af1[0]=(_Float16)u2.x; af1[1]=(_Float16)u2.y; af1[2]=(_Float16)u2.z; af1[3]=(_Float16)u2.w;
                af1[4]=(_Float16)u3.x; af1[5]=(_Float16)u3.y; af1[6]=(_Float16)u3.z; af1[7]=(_Float16)u3.w;
            }
        } else {
#pragma unroll
            for (int j = 0; j < 8; ++j) { af0[j] = (_Float16)0.f; af1[j] = (_Float16)0.f; }
        }
#pragma unroll
        for (int ct = 0; ct < 4; ++ct) {
            float4v c = {0.f, 0.f, 0.f, 0.f};
            c = __builtin_amdgcn_mfma_f32_16x16x32_f16(af0, bf[ct][0], c, 0, 0, 0);
            c = __builtin_amdgcn_mfma_f32_16x16x32_f16(af1, bf[ct][1], c, 0, 0, 0);
#pragma unroll
            for (int q = 0; q < 4; ++q) {
                int rr = base + kg * 4 + q;
                if (rr < N) yh[(size_t)rr * 64 + ct * 16 + c16] = __float2half_rn(c[q] * dinv[rr]);
            }
        }
    }
}

// 8 nodes per wave: group g (8 lanes) owns node wave*8+g entirely; lane i owns 16B chunk i.
// Per-group loop over own CSR segment (8-edge unroll), packed fp16 adds, NO cross-lane reduction.
__global__ __launch_bounds__(256) void k_agg(const int* __restrict__ starts,
                                             const int* __restrict__ srcs,   // pre-scaled *8
                                             const __half* __restrict__ yh,
                                             const float* __restrict__ dinv,
                                             const float* __restrict__ b,
                                             __half* __restrict__ xh, int N) {
    int wv = (blockIdx.x * blockDim.x + threadIdx.x) >> 6;
    int lane = threadIdx.x & 63;
    int g = lane >> 3, i = lane & 7;
    int node = wv * 8 + g;
    bool valid = node < N;
    const float4* y4 = (const float4*)yh;   // row = 8 float4 chunks
    __half2 a0, a1, a2, a3;
    a0 = a1 = a2 = a3 = __half2half2(__ushort_as_half((unsigned short)0));
    int s = 0, t = 0;
    if (valid) {
        s = starts[node]; t = starts[node + 1];
        float4 raw = y4[(size_t)node * 8 + i];   // self loop
        const __half2* h = (const __half2*)&raw;
        a0 = h[0]; a1 = h[1]; a2 = h[2]; a3 = h[3];
    }
    int e = s;
    for (; e + 7 < t; e += 8) {
        float4 r[8];
#pragma unroll
        for (int k = 0; k < 8; ++k) r[k] = y4[(size_t)srcs[e + k] + i];
#pragma unroll
        for (int k = 0; k < 8; ++k) {
            const __half2* h = (const __half2*)&r[k];
            a0 = __hadd2(a0, h[0]); a1 = __hadd2(a1, h[1]);
            a2 = __hadd2(a2, h[2]); a3 = __hadd2(a3, h[3]);
        }
    }
    for (; e + 3 < t; e += 4) {
        float4 r[4];
#pragma unroll
        for (int k = 0; k < 4; ++k) r[k] = y4[(size_t)srcs[e + k] + i];
#pragma unroll
        for (int k = 0; k < 4; ++k) {
            const __half2* h = (const __half2*)&r[k];
            a0 = __hadd2(a0, h[0]); a1 = __hadd2(a1, h[1]);
            a2 = __hadd2(a2, h[2]); a3 = __hadd2(a3, h[3]);
        }
    }
    for (; e < t; ++e) {
        float4 r0 = y4[(size_t)srcs[e] + i];
        const __half2* h0 = (const __half2*)&r0;
        a0 = __hadd2(a0, h0[0]); a1 = __hadd2(a1, h0[1]);
        a2 = __hadd2(a2, h0[2]); a3 = __hadd2(a3, h0[3]);
    }
    if (valid) {
        float d = dinv[node];
        float4 b0 = ((const float4*)b)[2 * i];
        float4 b1 = ((const float4*)b)[2 * i + 1];
        float bb[8] = {b0.x, b0.y, b0.z, b0.w, b1.x, b1.y, b1.z, b1.w};
        float2 f0 = __half22float2(a0), f1 = __half22float2(a1);
        float2 f2 = __half22float2(a2), f3 = __half22float2(a3);
        float sums[8] = {f0.x, f0.y, f1.x, f1.y, f2.x, f2.y, f3.x, f3.y};
        float o[8];
#pragma unroll
        for (int f = 0; f < 8; ++f) {
            float v = d * sums[f] + bb[f];
            o[f] = v / (1.f + __expf(-v));
        }
        float4 outv;
        __half2* oh = (__half2*)&outv;
#pragma unroll
        for (int p = 0; p < 4; ++p) oh[p] = __float22half2_rn(make_float2(o[2 * p], o[2 * p + 1]));
        ((float4*)xh)[(size_t)node * 8 + i] = outv;
    }
}

// Pool phase 1: wave-per-slice partial sums. Lane = feature; flush on graph change.
__global__ __launch_bounds__(256) void k_pool1(const __half* __restrict__ xh,
                                               const int* __restrict__ batch, int N, int chunk,
                                               float* __restrict__ sums) {
    int wvg = blockIdx.x * 4 + (threadIdx.x >> 6);
    int lane = threadIdx.x & 63;
    int lo = wvg * chunk;
    int hi = min(N, lo + chunk);
    if (lo >= hi) return;
    float acc = 0.f;
    int gcur = batch[lo];
    for (int n = lo; n < hi; ++n) {
        int gn = batch[n];
        if (gn != gcur) {
            atomicAdd(&sums[gcur * 64 + lane], acc);
            acc = 0.f;
            gcur = gn;
        }
        acc += __half2float(xh[(size_t)n * 64 + lane]);
    }
    atomicAdd(&sums[gcur * 64 + lane], acc);
}

// Pool phase 2: one 64-thread block per graph: mean, readout linear+relu, log_softmax
__global__ void k_readout(const float* __restrict__ sums, const int* __restrict__ batch, int N,
                          const float* __restrict__ Wro, const float* __restrict__ bro,
                          float* __restrict__ out, int C) {
    int g = blockIdx.x;
    int j = threadIdx.x;
    __shared__ float sp[64];
    __shared__ float sl[32];
    int lo = 0, hb = N;
    while (lo < hb) { int m = (lo + hb) >> 1; if (batch[m] < g) lo = m + 1; else hb = m; }
    int lo2 = lo, hi2 = N;
    while (lo2 < hi2) { int m = (lo2 + hi2) >> 1; if (batch[m] < g + 1) lo2 = m + 1; else hi2 = m; }
    float cnt = fmaxf((float)(hi2 - lo), 1.0f);
    sp[j] = sums[g * 64 + j] / cnt;
    __syncthreads();
    if (j < C) {
        float a = bro[j];
        for (int k = 0; k < 64; ++k) a += sp[k] * Wro[k * C + j];
        sl[j] = fmaxf(a, 0.f);
    }
    __syncthreads();
    if (j == 0) {
        float m = -1e30f;
        for (int c = 0; c < C; ++c) m = fmaxf(m, sl[c]);
        float sum = 0.f;
        for (int c = 0; c < C; ++c) sum += __expf(sl[c] - m);
        float lse = m + __logf(sum);
        for (int c = 0; c < C; ++c) out[g * C + c] = sl[c] - lse;
    }
}

static inline size_t align256(size_t v) { return (v + 255) & ~(size_t)255; }

extern "C" void kernel_launch(void* const* d_in, const int* in_sizes, int n_in,
                              void* d_out, int out_size, void* d_ws, size_t ws_size,
                              hipStream_t stream) {
    const float* x    = (const float*)d_in[0];
    const int*   ei   = (const int*)d_in[1];
    const int*   batch= (const int*)d_in[2];
    const float* W[3] = {(const float*)d_in[4], (const float*)d_in[6], (const float*)d_in[8]};
    const float* b[3] = {(const float*)d_in[5], (const float*)d_in[7], (const float*)d_in[9]};
    const float* Wro  = (const float*)d_in[10];
    const float* bro  = (const float*)d_in[11];

    int N = in_sizes[2];
    int E = in_sizes[1] / 2;
    int C = in_sizes[10] / 64;
    int G = out_size / C;

    const int* row = ei;          // sources
    const int* col = ei + E;      // targets

    int NB = (N + BNODES - 1) >> BSH;      // target buckets (<=1024)
    int Ec = (E + CH - 1) / CH;            // edges per chunk

    char* ws = (char*)d_ws;
    size_t off = 0;
    float* dinv    = (float*)(ws + off);        off = align256(off + (size_t)N * 4);
    int*   histG   = (int*)(ws + off);          off = align256(off + (size_t)CH * NB * 4);
    int*   btot    = (int*)(ws + off);          off = align256(off + (size_t)NB * 4);
    int*   bstart  = (int*)(ws + off);          off = align256(off + (size_t)(NB + 1) * 4);
    unsigned int* edges = (unsigned int*)(ws + off); off = align256(off + (size_t)E * 4);
    int*   srcs    = (int*)(ws + off);          off = align256(off + (size_t)E * 4);
    int*   starts  = (int*)(ws + off);          off = align256(off + (size_t)(N + 1) * 4);
    __half* yh     = (__half*)(ws + off);       off = align256(off + (size_t)N * 64 * 2);
    __half* xh     = (__half*)(ws + off);       off = align256(off + (size_t)N * 64 * 2);
    float* sums    = (float*)(ws + off);        off = align256(off + (size_t)G * 64 * 4);

    k_hist<<<CH, 256, 0, stream>>>(col, E, Ec, NB, histG);
    k_scanb<<<NB, 64, 0, stream>>>(histG, NB, btot);
    k_scant<<<1, 1024, 0, stream>>>(btot, NB, E, bstart);
    k_scatter<<<CH, 1024, 0, stream>>>(col, row, E, Ec, NB, histG, bstart, edges);
    k_sort2<<<NB, 512, 0, stream>>>(edges, bstart, N, E, NB, srcs, starts, dinv);

    int aggB = (N + 31) / 32;   // 8 nodes/wave, 4 waves/block = 32 nodes/block
    int gemmB = 1568;           // ~1 16-row tile per wave

    k_gemm<0><<<gemmB, 256, 0, stream>>>(x, W[0], dinv, yh, N);
    k_agg<<<aggB, 256, 0, stream>>>(starts, srcs, yh, dinv, b[0], xh, N);
    k_gemm<1><<<gemmB, 256, 0, stream>>>(xh, W[1], dinv, yh, N);
    k_agg<<<aggB, 256, 0, stream>>>(starts, srcs, yh, dinv, b[1], xh, N);
    k_gemm<1><<<gemmB, 256, 0, stream>>>(xh, W[2], dinv, yh, N);
    k_agg<<<aggB, 256, 0, stream>>>(starts, srcs, yh, dinv, b[2], xh, N);

    hipMemsetAsync(sums, 0, (size_t)G * 64 * sizeof(float), stream);
    int nwaves = 4096;
    int chunk = (N + nwaves - 1) / nwaves;
    k_pool1<<<nwaves / 4, 256, 0, stream>>>(xh, batch, N, chunk, sums);
    k_readout<<<G, 64, 0, stream>>>(sums, batch, N, Wro, bro, (float*)d_out, C);
}

// Round 11
// 205.011 us; speedup vs baseline: 10.7764x; 1.0084x over previous
//
#include <hip/hip_runtime.h>
#include <hip/hip_fp16.h>

// GCN: 3x (x = silu(Dinv A Dinv (x W) + b)) -> mean-pool -> relu(pooled@Wro+bro) -> log_softmax
// y = (x@W)*dinv[row] fp16; out[c] = dinv[c]*(sum_{r->c} y[r] + y[c]) + b; x' = silu(out) fp16.
// CSR built once via atomic-free two-level counting sort (bucket hist/scan/scatter + in-bucket sort).
// Aggregation: 8 nodes per wave (8 lanes/node), per-group CSR loop, packed fp16 adds, no reduction.
// Pooling: wave-per-slice partial sums (flush-on-graph-change) + tiny per-graph readout.
// sums[] zeroed inside k_scant (no hipMemsetAsync: the runtime fill kernel cost ~40us/replay).

#define CH 256          // edge chunks
#define BSH 7           // log2(nodes per bucket)
#define BNODES 128

typedef _Float16 half8 __attribute__((ext_vector_type(8)));
typedef float float4v __attribute__((ext_vector_type(4)));

// Phase 1: per-chunk histogram over target buckets (LDS atomics only)
__global__ __launch_bounds__(256) void k_hist(const int* __restrict__ col, int E, int Ec, int NB,
                                              int* __restrict__ histG) {
    __shared__ int h[1024];
    int c = blockIdx.x, tid = threadIdx.x;
    for (int i = tid; i < NB; i += 256) h[i] = 0;
    __syncthreads();
    int lo = c * Ec, hi = min(E, lo + Ec);
    for (int e = lo + tid; e < hi; e += 256) atomicAdd(&h[col[e] >> BSH], 1);
    __syncthreads();
    for (int i = tid; i < NB; i += 256) histG[c * NB + i] = h[i];
}

// Phase 2a: per bucket, exclusive scan across CH=256 chunks (one wave per bucket, 4 chunks/lane)
__global__ void k_scanb(int* __restrict__ histG, int NB, int* __restrict__ btot) {
    int b = blockIdx.x;
    int l = threadIdx.x;  // 0..63
    int v[4], p[4];
#pragma unroll
    for (int k = 0; k < 4; ++k) { v[k] = histG[(k * 64 + l) * NB + b]; p[k] = v[k]; }
    for (int off = 1; off < 64; off <<= 1) {
#pragma unroll
        for (int k = 0; k < 4; ++k) {
            int t = __shfl_up(p[k], off);
            if (l >= off) p[k] += t;
        }
    }
    int acc = 0;
#pragma unroll
    for (int k = 0; k < 4; ++k) {
        int tot = __shfl(p[k], 63);
        histG[(k * 64 + l) * NB + b] = acc + p[k] - v[k];
        acc += tot;
    }
    if (l == 0) btot[b] = acc;
}

// Phase 2b: exclusive scan of bucket totals -> bucket start offsets. Also zeroes sums[].
__global__ void k_scant(const int* __restrict__ btot, int NB, int E, int* __restrict__ bstart,
                        float* __restrict__ sums, int GF) {
    __shared__ int s[1024];
    int tid = threadIdx.x;
    for (int i = tid; i < GF; i += 1024) sums[i] = 0.f;
    int v = (tid < NB) ? btot[tid] : 0;
    s[tid] = v;
    __syncthreads();
    for (int off = 1; off < 1024; off <<= 1) {
        int t = (tid >= off) ? s[tid - off] : 0;
        __syncthreads();
        s[tid] += t;
        __syncthreads();
    }
    if (tid < NB) bstart[tid] = s[tid] - v;
    if (tid == 0) bstart[NB] = E;
}

// Phase 3: scatter edges into bucket-grouped order. LDS cursors, no global atomics.
__global__ __launch_bounds__(1024) void k_scatter(const int* __restrict__ col, const int* __restrict__ row,
                                                  int E, int Ec, int NB,
                                                  const int* __restrict__ histG,
                                                  const int* __restrict__ bstart,
                                                  unsigned int* __restrict__ edges) {
    __shared__ int cur[1024];
    int c = blockIdx.x, tid = threadIdx.x;
    for (int i = tid; i < NB; i += 1024) cur[i] = bstart[i] + histG[c * NB + i];
    __syncthreads();
    int lo = c * Ec, hi = min(E, lo + Ec);
    for (int e = lo + tid; e < hi; e += 1024) {
        int cc = col[e];
        int b = cc >> BSH;
        int pos = atomicAdd(&cur[b], 1);   // LDS atomic
        edges[pos] = (unsigned int)row[e] | ((unsigned int)(cc & (BNODES - 1)) << 25);
    }
}

// Phase 4: within each bucket, counting-sort edges by local node -> per-node CSR + dinv.
// srcs stored PRE-SCALED (*8) = float4-chunk index of the source row.
__global__ __launch_bounds__(512) void k_sort2(const unsigned int* __restrict__ edges,
                                               const int* __restrict__ bstart, int N, int E, int NB,
                                               int* __restrict__ srcs, int* __restrict__ starts,
                                               float* __restrict__ dinv) {
    __shared__ int cnt[BNODES];
    __shared__ int cur[BNODES];
    int b = blockIdx.x, tid = threadIdx.x;
    if (tid < BNODES) cnt[tid] = 0;
    __syncthreads();
    int lo = bstart[b], hi = bstart[b + 1];
    for (int e = lo + tid; e < hi; e += 512) atomicAdd(&cnt[edges[e] >> 25], 1);
    __syncthreads();
    if (tid < 64) {   // wave 0: exclusive scan of cnt[128], 2 elems/lane
        int v0 = cnt[tid], v1 = cnt[64 + tid];
        int p0 = v0, p1 = v1;
        for (int off = 1; off < 64; off <<= 1) {
            int t0 = __shfl_up(p0, off);
            int t1 = __shfl_up(p1, off);
            if (tid >= off) { p0 += t0; p1 += t1; }
        }
        int A = __shfl(p0, 63);
        cur[tid] = lo + p0 - v0;
        cur[64 + tid] = lo + A + p1 - v1;
    }
    __syncthreads();
    int ng = b * BNODES + tid;
    if (tid < BNODES && ng < N) {
        starts[ng] = cur[tid];
        dinv[ng] = rsqrtf((float)cnt[tid] + 1.0f);
    }
    if (b == 0 && tid == 0) starts[N] = E;
    __syncthreads();   // starts must be read out before cursors move
    for (int e = lo + tid; e < hi; e += 512) {
        unsigned int p = edges[e];
        int pos = atomicAdd(&cur[p >> 25], 1);   // LDS atomic
        srcs[pos] = (int)((p & 0x1FFFFFFu) << 3);   // pre-scaled: row * 8
    }
}

// MFMA GEMM: yh[r] = fp16((x[r] @ W) * dinv[r]).
template <int IN_HALF>
__global__ __launch_bounds__(256) void k_gemm(const void* __restrict__ xin,
                                              const float* __restrict__ W,
                                              const float* __restrict__ dinv,
                                              __half* __restrict__ yh, int N) {
    __shared__ float sW[64 * 64];
    int tid = threadIdx.x;
    for (int k = tid; k < 4096; k += 256) sW[k] = W[k];
    __syncthreads();
    int lane = tid & 63, wv = tid >> 6;
    int c16 = lane & 15, kg = lane >> 4;
    half8 bf[4][2];
#pragma unroll
    for (int ct = 0; ct < 4; ++ct)
#pragma unroll
        for (int ks = 0; ks < 2; ++ks)
#pragma unroll
            for (int j = 0; j < 8; ++j)
                bf[ct][ks][j] = (_Float16)sW[(ks * 32 + kg * 8 + j) * 64 + ct * 16 + c16];

    int tiles = (N + 15) >> 4;
    for (int t = blockIdx.x * 4 + wv; t < tiles; t += gridDim.x * 4) {
        int base = t << 4;
        int arow = base + c16;
        half8 af0, af1;
        if (arow < N) {
            if (IN_HALF) {
                const __half* xh = (const __half*)xin;
                af0 = *(const half8*)(xh + (size_t)arow * 64 + kg * 8);
                af1 = *(const half8*)(xh + (size_t)arow * 64 + 32 + kg * 8);
            } else {
                const float* xf = (const float*)xin;
                float4 u0 = *(const float4*)(xf + (size_t)arow * 64 + kg * 8);
                float4 u1 = *(const float4*)(xf + (size_t)arow * 64 + kg * 8 + 4);
                float4 u2 = *(const float4*)(xf + (size_t)arow * 64 + 32 + kg * 8);
                float4 u3 = *(const float4*)(xf + (size_t)arow * 64 + 32 + kg * 8 + 4);
                af0[0]=(_Float16)u0.x; af0[1]=(_Float16)u0.y; af0[2]=(_Float16)u0.z; af0[3]=(_Float16)u0.w;
                af0[4]=(_Float16)u1.x; af0[5]=(_Float16)u1.y; af0[6]=(_Float16)u1.z; af0[7]=(_Float16)u1.w;
                af1[0]=(_Float16)u2.x; af1[1]=(_Float16)u2.y; af1[2]=(_Float16)u2.z; af1[3]=(_Float16)u2.w;
                af1[4]=(_Float16)u3.x; af1[5]=(_Float16)u3.y; af1[6]=(_Float16)u3.z; af1[7]=(_Float16)u3.w;
            }
        } else {
#pragma unroll
            for (int j = 0; j < 8; ++j) { af0[j] = (_Float16)0.f; af1[j] = (_Float16)0.f; }
        }
#pragma unroll
        for (int ct = 0; ct < 4; ++ct) {
            float4v c = {0.f, 0.f, 0.f, 0.f};
            c = __builtin_amdgcn_mfma_f32_16x16x32_f16(af0, bf[ct][0], c, 0, 0, 0);
            c = __builtin_amdgcn_mfma_f32_16x16x32_f16(af1, bf[ct][1], c, 0, 0, 0);
#pragma unroll
            for (int q = 0; q < 4; ++q) {
                int rr = base + kg * 4 + q;
                if (rr < N) yh[(size_t)rr * 64 + ct * 16 + c16] = __float2half_rn(c[q] * dinv[rr]);
            }
        }
    }
}

// 8 nodes per wave: group g (8 lanes) owns node wave*8+g entirely; lane i owns 16B chunk i.
// Per-group loop over own CSR segment (8-edge unroll), packed fp16 adds, NO cross-lane reduction.
__global__ __launch_bounds__(256) void k_agg(const int* __restrict__ starts,
                                             const int* __restrict__ srcs,   // pre-scaled *8
                                             const __half* __restrict__ yh,
                                             const float* __restrict__ dinv,
                                             const float* __restrict__ b,
                                             __half* __restrict__ xh, int N) {
    int wv = (blockIdx.x * blockDim.x + threadIdx.x) >> 6;
    int lane = threadIdx.x & 63;
    int g = lane >> 3, i = lane & 7;
    int node = wv * 8 + g;
    bool valid = node < N;
    const float4* y4 = (const float4*)yh;   // row = 8 float4 chunks
    __half2 a0, a1, a2, a3;
    a0 = a1 = a2 = a3 = __half2half2(__ushort_as_half((unsigned short)0));
    int s = 0, t = 0;
    if (valid) {
        s = starts[node]; t = starts[node + 1];
        float4 raw = y4[(size_t)node * 8 + i];   // self loop
        const __half2* h = (const __half2*)&raw;
        a0 = h[0]; a1 = h[1]; a2 = h[2]; a3 = h[3];
    }
    int e = s;
    for (; e + 7 < t; e += 8) {
        float4 r[8];
#pragma unroll
        for (int k = 0; k < 8; ++k) r[k] = y4[(size_t)srcs[e + k] + i];
#pragma unroll
        for (int k = 0; k < 8; ++k) {
            const __half2* h = (const __half2*)&r[k];
            a0 = __hadd2(a0, h[0]); a1 = __hadd2(a1, h[1]);
            a2 = __hadd2(a2, h[2]); a3 = __hadd2(a3, h[3]);
        }
    }
    for (; e + 3 < t; e += 4) {
        float4 r[4];
#pragma unroll
        for (int k = 0; k < 4; ++k) r[k] = y4[(size_t)srcs[e + k] + i];
#pragma unroll
        for (int k = 0; k < 4; ++k) {
            const __half2* h = (const __half2*)&r[k];
            a0 = __hadd2(a0, h[0]); a1 = __hadd2(a1, h[1]);
            a2 = __hadd2(a2, h[2]); a3 = __hadd2(a3, h[3]);
        }
    }
    for (; e < t; ++e) {
        float4 r0 = y4[(size_t)srcs[e] + i];
        const __half2* h0 = (const __half2*)&r0;
        a0 = __hadd2(a0, h0[0]); a1 = __hadd2(a1, h0[1]);
        a2 = __hadd2(a2, h0[2]); a3 = __hadd2(a3, h0[3]);
    }
    if (valid) {
        float d = dinv[node];
        float4 b0 = ((const float4*)b)[2 * i];
        float4 b1 = ((const float4*)b)[2 * i + 1];
        float bb[8] = {b0.x, b0.y, b0.z, b0.w, b1.x, b1.y, b1.z, b1.w};
        float2 f0 = __half22float2(a0), f1 = __half22float2(a1);
        float2 f2 = __half22float2(a2), f3 = __half22float2(a3);
        float sums[8] = {f0.x, f0.y, f1.x, f1.y, f2.x, f2.y, f3.x, f3.y};
        float o[8];
#pragma unroll
        for (int f = 0; f < 8; ++f) {
            float v = d * sums[f] + bb[f];
            o[f] = v / (1.f + __expf(-v));
        }
        float4 outv;
        __half2* oh = (__half2*)&outv;
#pragma unroll
        for (int p = 0; p < 4; ++p) oh[p] = __float22half2_rn(make_float2(o[2 * p], o[2 * p + 1]));
        ((float4*)xh)[(size_t)node * 8 + i] = outv;
    }
}

// Pool phase 1: wave-per-slice partial sums. Lane = feature; flush on graph change.
__global__ __launch_bounds__(256) void k_pool1(const __half* __restrict__ xh,
                                               const int* __restrict__ batch, int N, int chunk,
                                               float* __restrict__ sums) {
    int wvg = blockIdx.x * 4 + (threadIdx.x >> 6);
    int lane = threadIdx.x & 63;
    int lo = wvg * chunk;
    int hi = min(N, lo + chunk);
    if (lo >= hi) return;
    float acc = 0.f;
    int gcur = batch[lo];
    for (int n = lo; n < hi; ++n) {
        int gn = batch[n];
        if (gn != gcur) {
            atomicAdd(&sums[gcur * 64 + lane], acc);
            acc = 0.f;
            gcur = gn;
        }
        acc += __half2float(xh[(size_t)n * 64 + lane]);
    }
    atomicAdd(&sums[gcur * 64 + lane], acc);
}

// Pool phase 2: one 64-thread block per graph: mean, readout linear+relu, log_softmax
__global__ void k_readout(const float* __restrict__ sums, const int* __restrict__ batch, int N,
                          const float* __restrict__ Wro, const float* __restrict__ bro,
                          float* __restrict__ out, int C) {
    int g = blockIdx.x;
    int j = threadIdx.x;
    __shared__ float sp[64];
    __shared__ float sl[32];
    int lo = 0, hb = N;
    while (lo < hb) { int m = (lo + hb) >> 1; if (batch[m] < g) lo = m + 1; else hb = m; }
    int lo2 = lo, hi2 = N;
    while (lo2 < hi2) { int m = (lo2 + hi2) >> 1; if (batch[m] < g + 1) lo2 = m + 1; else hi2 = m; }
    float cnt = fmaxf((float)(hi2 - lo), 1.0f);
    sp[j] = sums[g * 64 + j] / cnt;
    __syncthreads();
    if (j < C) {
        float a = bro[j];
        for (int k = 0; k < 64; ++k) a += sp[k] * Wro[k * C + j];
        sl[j] = fmaxf(a, 0.f);
    }
    __syncthreads();
    if (j == 0) {
        float m = -1e30f;
        for (int c = 0; c < C; ++c) m = fmaxf(m, sl[c]);
        float sum = 0.f;
        for (int c = 0; c < C; ++c) sum += __expf(sl[c] - m);
        float lse = m + __logf(sum);
        for (int c = 0; c < C; ++c) out[g * C + c] = sl[c] - lse;
    }
}

static inline size_t align256(size_t v) { return (v + 255) & ~(size_t)255; }

extern "C" void kernel_launch(void* const* d_in, const int* in_sizes, int n_in,
                              void* d_out, int out_size, void* d_ws, size_t ws_size,
                              hipStream_t stream) {
    const float* x    = (const float*)d_in[0];
    const int*   ei   = (const int*)d_in[1];
    const int*   batch= (const int*)d_in[2];
    const float* W[3] = {(const float*)d_in[4], (const float*)d_in[6], (const float*)d_in[8]};
    const float* b[3] = {(const float*)d_in[5], (const float*)d_in[7], (const float*)d_in[9]};
    const float* Wro  = (const float*)d_in[10];
    const float* bro  = (const float*)d_in[11];

    int N = in_sizes[2];
    int E = in_sizes[1] / 2;
    int C = in_sizes[10] / 64;
    int G = out_size / C;

    const int* row = ei;          // sources
    const int* col = ei + E;      // targets

    int NB = (N + BNODES - 1) >> BSH;      // target buckets (<=1024)
    int Ec = (E + CH - 1) / CH;            // edges per chunk

    char* ws = (char*)d_ws;
    size_t off = 0;
    float* dinv    = (float*)(ws + off);        off = align256(off + (size_t)N * 4);
    int*   histG   = (int*)(ws + off);          off = align256(off + (size_t)CH * NB * 4);
    int*   btot    = (int*)(ws + off);          off = align256(off + (size_t)NB * 4);
    int*   bstart  = (int*)(ws + off);          off = align256(off + (size_t)(NB + 1) * 4);
    unsigned int* edges = (unsigned int*)(ws + off); off = align256(off + (size_t)E * 4);
    int*   srcs    = (int*)(ws + off);          off = align256(off + (size_t)E * 4);
    int*   starts  = (int*)(ws + off);          off = align256(off + (size_t)(N + 1) * 4);
    __half* yh     = (__half*)(ws + off);       off = align256(off + (size_t)N * 64 * 2);
    __half* xh     = (__half*)(ws + off);       off = align256(off + (size_t)N * 64 * 2);
    float* sums    = (float*)(ws + off);        off = align256(off + (size_t)G * 64 * 4);

    k_hist<<<CH, 256, 0, stream>>>(col, E, Ec, NB, histG);
    k_scanb<<<NB, 64, 0, stream>>>(histG, NB, btot);
    k_scant<<<1, 1024, 0, stream>>>(btot, NB, E, bstart, sums, G * 64);
    k_scatter<<<CH, 1024, 0, stream>>>(col, row, E, Ec, NB, histG, bstart, edges);
    k_sort2<<<NB, 512, 0, stream>>>(edges, bstart, N, E, NB, srcs, starts, dinv);

    int aggB = (N + 31) / 32;   // 8 nodes/wave, 4 waves/block = 32 nodes/block
    int gemmB = 1568;           // ~1 16-row tile per wave

    k_gemm<0><<<gemmB, 256, 0, stream>>>(x, W[0], dinv, yh, N);
    k_agg<<<aggB, 256, 0, stream>>>(starts, srcs, yh, dinv, b[0], xh, N);
    k_gemm<1><<<gemmB, 256, 0, stream>>>(xh, W[1], dinv, yh, N);
    k_agg<<<aggB, 256, 0, stream>>>(starts, srcs, yh, dinv, b[1], xh, N);
    k_gemm<1><<<gemmB, 256, 0, stream>>>(xh, W[2], dinv, yh, N);
    k_agg<<<aggB, 256, 0, stream>>>(starts, srcs, yh, dinv, b[2], xh, N);

    int nwaves = 4096;
    int chunk = (N + nwaves - 1) / nwaves;
    k_pool1<<<nwaves / 4, 256, 0, stream>>>(xh, batch, N, chunk, sums);
    k_readout<<<G, 64, 0, stream>>>(sums, batch, N, Wro, bro, (float*)d_out, C);
}

// Round 15
// 199.505 us; speedup vs baseline: 11.0738x; 1.0276x over previous
//
#include <hip/hip_runtime.h>
#include <hip/hip_fp16.h>

// GCN: 3x (x = silu(Dinv A Dinv (x W) + b)) -> mean-pool -> relu(pooled@Wro+bro) -> log_softmax
// y = (x@W)*dinv[row] fp16; out[c] = dinv[c]*(sum_{r->c} y[r] + y[c]) + b; x' = silu(out) fp16.
// CSR built once via atomic-free two-level counting sort (round-11 proven hist/scan/scatter/sort).
// GEMM: MFMA 16x16x32 f16, operand-swapped (lane owns one x-row; 4 consecutive features/reg ->
//       packed 8B stores), W fragments pre-permuted fp16 by k_wt (no LDS, no syncthreads in loop).
// Aggregation: 8 nodes per wave (8 lanes/node), per-group CSR loop, packed fp16 adds, no reduction.
// Pooling: wave-per-slice partial sums + tiny per-graph readout. sums zeroed in k_scant.

#define CH 256          // edge chunks
#define BSH 7           // log2(nodes per bucket)
#define BNODES 128

typedef _Float16 half8 __attribute__((ext_vector_type(8)));
typedef float float4v __attribute__((ext_vector_type(4)));

// W fragment pre-permute: Wt[l][ct][ks][kg][c16][j] = (half)W_l[(ks*32+kg*8+j)*64 + ct*16+c16]
__global__ void k_wt(const float* __restrict__ W0, const float* __restrict__ W1,
                     const float* __restrict__ W2, __half* __restrict__ Wt) {
    const float* Ws[3] = {W0, W1, W2};
    const float* W = Ws[blockIdx.x];
    __half* out = Wt + blockIdx.x * 4096;
    for (int idx = threadIdx.x; idx < 4096; idx += 256) {
        int k = idx >> 6, feat = idx & 63;
        int ks = k >> 5, kg = (k >> 3) & 3, j = k & 7;
        int ct = feat >> 4, c16 = feat & 15;
        out[((ct * 2 + ks) * 4 + kg) * 128 + c16 * 8 + j] = __float2half_rn(W[k * 64 + feat]);
    }
}

// Phase 1: per-chunk histogram over target buckets (LDS atomics only). [round-11 proven]
__global__ __launch_bounds__(256) void k_hist(const int* __restrict__ col, int E, int Ec, int NB,
                                              int* __restrict__ histG) {
    __shared__ int h[1024];
    int c = blockIdx.x, tid = threadIdx.x;
    for (int i = tid; i < NB; i += 256) h[i] = 0;
    __syncthreads();
    int lo = c * Ec, hi = min(E, lo + Ec);
    for (int e = lo + tid; e < hi; e += 256) atomicAdd(&h[col[e] >> BSH], 1);
    __syncthreads();
    for (int i = tid; i < NB; i += 256) histG[c * NB + i] = h[i];
}

// Phase 2a: per bucket, exclusive scan across CH=256 chunks (one wave per bucket, 4 chunks/lane)
__global__ void k_scanb(int* __restrict__ histG, int NB, int* __restrict__ btot) {
    int b = blockIdx.x;
    int l = threadIdx.x;  // 0..63
    int v[4], p[4];
#pragma unroll
    for (int k = 0; k < 4; ++k) { v[k] = histG[(k * 64 + l) * NB + b]; p[k] = v[k]; }
    for (int off = 1; off < 64; off <<= 1) {
#pragma unroll
        for (int k = 0; k < 4; ++k) {
            int t = __shfl_up(p[k], off);
            if (l >= off) p[k] += t;
        }
    }
    int acc = 0;
#pragma unroll
    for (int k = 0; k < 4; ++k) {
        int tot = __shfl(p[k], 63);
        histG[(k * 64 + l) * NB + b] = acc + p[k] - v[k];
        acc += tot;
    }
    if (l == 0) btot[b] = acc;
}

// Phase 2b: exclusive scan of bucket totals -> bucket start offsets. Also zeroes sums[].
__global__ void k_scant(const int* __restrict__ btot, int NB, int E, int* __restrict__ bstart,
                        float* __restrict__ sums, int GF) {
    __shared__ int s[1024];
    int tid = threadIdx.x;
    for (int i = tid; i < GF; i += 1024) sums[i] = 0.f;
    int v = (tid < NB) ? btot[tid] : 0;
    s[tid] = v;
    __syncthreads();
    for (int off = 1; off < 1024; off <<= 1) {
        int t = (tid >= off) ? s[tid - off] : 0;
        __syncthreads();
        s[tid] += t;
        __syncthreads();
    }
    if (tid < NB) bstart[tid] = s[tid] - v;
    if (tid == 0) bstart[NB] = E;
}

// Phase 3: scatter edges into bucket-grouped order. LDS cursors, no global atomics.
// [round-11 proven: cursor indexed by BUCKET col>>BSH, payload packs row | (col&127)<<25]
__global__ __launch_bounds__(1024) void k_scatter(const int* __restrict__ col, const int* __restrict__ row,
                                                  int E, int Ec, int NB,
                                                  const int* __restrict__ histG,
                                                  const int* __restrict__ bstart,
                                                  unsigned int* __restrict__ edges) {
    __shared__ int cur[1024];
    int c = blockIdx.x, tid = threadIdx.x;
    for (int i = tid; i < NB; i += 1024) cur[i] = bstart[i] + histG[c * NB + i];
    __syncthreads();
    int lo = c * Ec, hi = min(E, lo + Ec);
    for (int e = lo + tid; e < hi; e += 1024) {
        int cc = col[e];
        int b = cc >> BSH;
        int pos = atomicAdd(&cur[b], 1);   // LDS atomic
        edges[pos] = (unsigned int)row[e] | ((unsigned int)(cc & (BNODES - 1)) << 25);
    }
}

// Phase 4: within each bucket, counting-sort edges by local node -> per-node CSR + dinv.
// srcs stored PRE-SCALED (*8) = float4-chunk index of the source row.
__global__ __launch_bounds__(512) void k_sort2(const unsigned int* __restrict__ edges,
                                               const int* __restrict__ bstart, int N, int E, int NB,
                                               int* __restrict__ srcs, int* __restrict__ starts,
                                               float* __restrict__ dinv) {
    __shared__ int cnt[BNODES];
    __shared__ int cur[BNODES];
    int b = blockIdx.x, tid = threadIdx.x;
    if (tid < BNODES) cnt[tid] = 0;
    __syncthreads();
    int lo = bstart[b], hi = bstart[b + 1];
    for (int e = lo + tid; e < hi; e += 512) atomicAdd(&cnt[edges[e] >> 25], 1);
    __syncthreads();
    if (tid < 64) {   // wave 0: exclusive scan of cnt[128], 2 elems/lane
        int v0 = cnt[tid], v1 = cnt[64 + tid];
        int p0 = v0, p1 = v1;
        for (int off = 1; off < 64; off <<= 1) {
            int t0 = __shfl_up(p0, off);
            int t1 = __shfl_up(p1, off);
            if (tid >= off) { p0 += t0; p1 += t1; }
        }
        int A = __shfl(p0, 63);
        cur[tid] = lo + p0 - v0;
        cur[64 + tid] = lo + A + p1 - v1;
    }
    __syncthreads();
    int ng = b * BNODES + tid;
    if (tid < BNODES && ng < N) {
        starts[ng] = cur[tid];
        dinv[ng] = rsqrtf((float)cnt[tid] + 1.0f);
    }
    if (b == 0 && tid == 0) starts[N] = E;
    __syncthreads();   // starts must be read out before cursors move
    for (int e = lo + tid; e < hi; e += 512) {
        unsigned int p = edges[e];
        int pos = atomicAdd(&cur[p >> 25], 1);   // LDS atomic
        srcs[pos] = (int)((p & 0x1FFFFFFu) << 3);   // pre-scaled: row * 8
    }
}

// MFMA GEMM: yh[r] = fp16((x[r] @ W) * dinv[r]).
// Operand-swapped: D = mfma(Wfrag, xfrag) -> A-role m = lane&15 = output feature (within ct-tile),
// B-role n = lane&15 = x-row. D: col(lane&15) = x-row, row((lane>>4)*4+q) = feature ct*16+kg*4+q.
// -> lane owns one x-row; 4 consecutive features per ct -> packed 8B store. Wt fragments global.
template <int IN_HALF>
__global__ __launch_bounds__(256) void k_gemm(const void* __restrict__ xin,
                                              const __half* __restrict__ Wt,
                                              const float* __restrict__ dinv,
                                              __half* __restrict__ yh, int N) {
    int tid = threadIdx.x;
    int lane = tid & 63, wv = tid >> 6;
    int c16 = lane & 15, kg = lane >> 4;
    const _Float16* wt = (const _Float16*)Wt;
    half8 bf[4][2];
#pragma unroll
    for (int ct = 0; ct < 4; ++ct)
#pragma unroll
        for (int ks = 0; ks < 2; ++ks)
            bf[ct][ks] = *(const half8*)(wt + ((ct * 2 + ks) * 4 + kg) * 128 + c16 * 8);

    int tiles = (N + 15) >> 4;
    for (int t = blockIdx.x * 4 + wv; t < tiles; t += gridDim.x * 4) {
        int base = t << 4;
        int arow = base + c16;
        bool valid = arow < N;
        half8 af0, af1;
        if (valid) {
            if (IN_HALF) {
                const __half* xh = (const __half*)xin;
                af0 = *(const half8*)(xh + (size_t)arow * 64 + kg * 8);
                af1 = *(const half8*)(xh + (size_t)arow * 64 + 32 + kg * 8);
            } else {
                const float* xf = (const float*)xin;
                float4 u0 = *(const float4*)(xf + (size_t)arow * 64 + kg * 8);
                float4 u1 = *(const float4*)(xf + (size_t)arow * 64 + kg * 8 + 4);
                float4 u2 = *(const float4*)(xf + (size_t)arow * 64 + 32 + kg * 8);
                float4 u3 = *(const float4*)(xf + (size_t)arow * 64 + 32 + kg * 8 + 4);
                af0[0]=(_Float16)u0.x; af0[1]=(_Float16)u0.y; af0[2]=(_Float16)u0.z; af0[3]=(_Float16)u0.w;
                af0[4]=(_Float16)u1.x; af0[5]=(_Float16)u1.y; af0[6]=(_Float16)u1.z; af0[7]=(_Float16)u1.w;
                af1[0]=(_Float16)u2.x; af1[1]=(_Float16)u2.y; af1[2]=(_Float16)u2.z; af1[3]=(_Float16)u2.w;
                af1[4]=(_Float16)u3.x; af1[5]=(_Float16)u3.y; af1[6]=(_Float16)u3.z; af1[7]=(_Float16)u3.w;
            }
        } else {
#pragma unroll
            for (int j = 0; j < 8; ++j) { af0[j] = (_Float16)0.f; af1[j] = (_Float16)0.f; }
        }
        float d = valid ? dinv[arow] : 0.f;
#pragma unroll
        for (int ct = 0; ct < 4; ++ct) {
            float4v c = {0.f, 0.f, 0.f, 0.f};
            c = __builtin_amdgcn_mfma_f32_16x16x32_f16(bf[ct][0], af0, c, 0, 0, 0);
            c = __builtin_amdgcn_mfma_f32_16x16x32_f16(bf[ct][1], af1, c, 0, 0, 0);
            if (valid) {
                float2 st;
                __half2* hp = (__half2*)&st;
                hp[0] = __float22half2_rn(make_float2(c[0] * d, c[1] * d));
                hp[1] = __float22half2_rn(make_float2(c[2] * d, c[3] * d));
                *(float2*)(yh + (size_t)arow * 64 + ct * 16 + kg * 4) = st;
            }
        }
    }
}

// 8 nodes per wave: group g (8 lanes) owns node wave*8+g entirely; lane i owns 16B chunk i.
// Per-group loop over own CSR segment (8-edge unroll), packed fp16 adds, NO cross-lane reduction.
__global__ __launch_bounds__(256) void k_agg(const int* __restrict__ starts,
                                             const int* __restrict__ srcs,   // pre-scaled *8
                                             const __half* __restrict__ yh,
                                             const float* __restrict__ dinv,
                                             const float* __restrict__ b,
                                             __half* __restrict__ xh, int N) {
    int wv = (blockIdx.x * blockDim.x + threadIdx.x) >> 6;
    int lane = threadIdx.x & 63;
    int g = lane >> 3, i = lane & 7;
    int node = wv * 8 + g;
    bool valid = node < N;
    const float4* y4 = (const float4*)yh;   // row = 8 float4 chunks
    __half2 a0, a1, a2, a3;
    a0 = a1 = a2 = a3 = __half2half2(__ushort_as_half((unsigned short)0));
    int s = 0, t = 0;
    if (valid) {
        s = starts[node]; t = starts[node + 1];
        float4 raw = y4[(size_t)node * 8 + i];   // self loop
        const __half2* h = (const __half2*)&raw;
        a0 = h[0]; a1 = h[1]; a2 = h[2]; a3 = h[3];
    }
    int e = s;
    for (; e + 7 < t; e += 8) {
        float4 r[8];
#pragma unroll
        for (int k = 0; k < 8; ++k) r[k] = y4[(size_t)srcs[e + k] + i];
#pragma unroll
        for (int k = 0; k < 8; ++k) {
            const __half2* h = (const __half2*)&r[k];
            a0 = __hadd2(a0, h[0]); a1 = __hadd2(a1, h[1]);
            a2 = __hadd2(a2, h[2]); a3 = __hadd2(a3, h[3]);
        }
    }
    for (; e + 3 < t; e += 4) {
        float4 r[4];
#pragma unroll
        for (int k = 0; k < 4; ++k) r[k] = y4[(size_t)srcs[e + k] + i];
#pragma unroll
        for (int k = 0; k < 4; ++k) {
            const __half2* h = (const __half2*)&r[k];
            a0 = __hadd2(a0, h[0]); a1 = __hadd2(a1, h[1]);
            a2 = __hadd2(a2, h[2]); a3 = __hadd2(a3, h[3]);
        }
    }
    for (; e < t; ++e) {
        float4 r0 = y4[(size_t)srcs[e] + i];
        const __half2* h0 = (const __half2*)&r0;
        a0 = __hadd2(a0, h0[0]); a1 = __hadd2(a1, h0[1]);
        a2 = __hadd2(a2, h0[2]); a3 = __hadd2(a3, h0[3]);
    }
    if (valid) {
        float d = dinv[node];
        float4 b0 = ((const float4*)b)[2 * i];
        float4 b1 = ((const float4*)b)[2 * i + 1];
        float bb[8] = {b0.x, b0.y, b0.z, b0.w, b1.x, b1.y, b1.z, b1.w};
        float2 f0 = __half22float2(a0), f1 = __half22float2(a1);
        float2 f2 = __half22float2(a2), f3 = __half22float2(a3);
        float sums[8] = {f0.x, f0.y, f1.x, f1.y, f2.x, f2.y, f3.x, f3.y};
        float o[8];
#pragma unroll
        for (int f = 0; f < 8; ++f) {
            float v = d * sums[f] + bb[f];
            o[f] = v / (1.f + __expf(-v));
        }
        float4 outv;
        __half2* oh = (__half2*)&outv;
#pragma unroll
        for (int p = 0; p < 4; ++p) oh[p] = __float22half2_rn(make_float2(o[2 * p], o[2 * p + 1]));
        ((float4*)xh)[(size_t)node * 8 + i] = outv;
    }
}

// Pool phase 1: wave-per-slice partial sums. Lane = feature; flush on graph change.
__global__ __launch_bounds__(256) void k_pool1(const __half* __restrict__ xh,
                                               const int* __restrict__ batch, int N, int chunk,
                                               float* __restrict__ sums) {
    int wvg = blockIdx.x * 4 + (threadIdx.x >> 6);
    int lane = threadIdx.x & 63;
    int lo = wvg * chunk;
    int hi = min(N, lo + chunk);
    if (lo >= hi) return;
    float acc = 0.f;
    int gcur = batch[lo];
    for (int n = lo; n < hi; ++n) {
        int gn = batch[n];
        if (gn != gcur) {
            atomicAdd(&sums[gcur * 64 + lane], acc);
            acc = 0.f;
            gcur = gn;
        }
        acc += __half2float(xh[(size_t)n * 64 + lane]);
    }
    atomicAdd(&sums[gcur * 64 + lane], acc);
}

// Pool phase 2: one 64-thread block per graph: mean, readout linear+relu, log_softmax
__global__ void k_readout(const float* __restrict__ sums, const int* __restrict__ batch, int N,
                          const float* __restrict__ Wro, const float* __restrict__ bro,
                          float* __restrict__ out, int C) {
    int g = blockIdx.x;
    int j = threadIdx.x;
    __shared__ float sp[64];
    __shared__ float sl[32];
    int lo = 0, hb = N;
    while (lo < hb) { int m = (lo + hb) >> 1; if (batch[m] < g) lo = m + 1; else hb = m; }
    int lo2 = lo, hi2 = N;
    while (lo2 < hi2) { int m = (lo2 + hi2) >> 1; if (batch[m] < g + 1) lo2 = m + 1; else hi2 = m; }
    float cnt = fmaxf((float)(hi2 - lo), 1.0f);
    sp[j] = sums[g * 64 + j] / cnt;
    __syncthreads();
    if (j < C) {
        float a = bro[j];
        for (int k = 0; k < 64; ++k) a += sp[k] * Wro[k * C + j];
        sl[j] = fmaxf(a, 0.f);
    }
    __syncthreads();
    if (j == 0) {
        float m = -1e30f;
        for (int c = 0; c < C; ++c) m = fmaxf(m, sl[c]);
        float sum = 0.f;
        for (int c = 0; c < C; ++c) sum += __expf(sl[c] - m);
        float lse = m + __logf(sum);
        for (int c = 0; c < C; ++c) out[g * C + c] = sl[c] - lse;
    }
}

static inline size_t align256(size_t v) { return (v + 255) & ~(size_t)255; }

extern "C" void kernel_launch(void* const* d_in, const int* in_sizes, int n_in,
                              void* d_out, int out_size, void* d_ws, size_t ws_size,
                              hipStream_t stream) {
    const float* x    = (const float*)d_in[0];
    const int*   ei   = (const int*)d_in[1];
    const int*   batch= (const int*)d_in[2];
    const float* W[3] = {(const float*)d_in[4], (const float*)d_in[6], (const float*)d_in[8]};
    const float* b[3] = {(const float*)d_in[5], (const float*)d_in[7], (const float*)d_in[9]};
    const float* Wro  = (const float*)d_in[10];
    const float* bro  = (const float*)d_in[11];

    int N = in_sizes[2];
    int E = in_sizes[1] / 2;
    int C = in_sizes[10] / 64;
    int G = out_size / C;

    const int* row = ei;          // sources
    const int* col = ei + E;      // targets

    int NB = (N + BNODES - 1) >> BSH;      // target buckets (<=1024)
    int Ec = (E + CH - 1) / CH;            // edges per chunk

    char* ws = (char*)d_ws;
    size_t off = 0;
    float* dinv    = (float*)(ws + off);        off = align256(off + (size_t)N * 4);
    int*   histG   = (int*)(ws + off);          off = align256(off + (size_t)CH * NB * 4);
    int*   btot    = (int*)(ws + off);          off = align256(off + (size_t)NB * 4);
    int*   bstart  = (int*)(ws + off);          off = align256(off + (size_t)(NB + 1) * 4);
    unsigned int* edges  = (unsigned int*)(ws + off); off = align256(off + (size_t)E * 4);
    int*   srcs    = (int*)(ws + off);          off = align256(off + (size_t)E * 4);
    int*   starts  = (int*)(ws + off);          off = align256(off + (size_t)(N + 1) * 4);
    __half* yh     = (__half*)(ws + off);       off = align256(off + (size_t)N * 64 * 2);
    __half* xh     = (__half*)(ws + off);       off = align256(off + (size_t)N * 64 * 2);
    float* sums    = (float*)(ws + off);        off = align256(off + (size_t)G * 64 * 4);
    __half* Wt     = (__half*)(ws + off);       off = align256(off + (size_t)3 * 4096 * 2);

    k_wt<<<3, 256, 0, stream>>>(W[0], W[1], W[2], Wt);
    k_hist<<<CH, 256, 0, stream>>>(col, E, Ec, NB, histG);
    k_scanb<<<NB, 64, 0, stream>>>(histG, NB, btot);
    k_scant<<<1, 1024, 0, stream>>>(btot, NB, E, bstart, sums, G * 64);
    k_scatter<<<CH, 1024, 0, stream>>>(col, row, E, Ec, NB, histG, bstart, edges);
    k_sort2<<<NB, 512, 0, stream>>>(edges, bstart, N, E, NB, srcs, starts, dinv);

    int aggB = (N + 31) / 32;   // 8 nodes/wave, 4 waves/block = 32 nodes/block
    int gemmB = 1568;           // ~1 16-row tile per wave

    k_gemm<0><<<gemmB, 256, 0, stream>>>(x, Wt, dinv, yh, N);
    k_agg<<<aggB, 256, 0, stream>>>(starts, srcs, yh, dinv, b[0], xh, N);
    k_gemm<1><<<gemmB, 256, 0, stream>>>(xh, Wt + 4096, dinv, yh, N);
    k_agg<<<aggB, 256, 0, stream>>>(starts, srcs, yh, dinv, b[1], xh, N);
    k_gemm<1><<<gemmB, 256, 0, stream>>>(xh, Wt + 8192, dinv, yh, N);
    k_agg<<<aggB, 256, 0, stream>>>(starts, srcs, yh, dinv, b[2], xh, N);

    int nwaves = 4096;
    int chunk = (N + nwaves - 1) / nwaves;
    k_pool1<<<nwaves / 4, 256, 0, stream>>>(xh, batch, N, chunk, sums);
    k_readout<<<G, 64, 0, stream>>>(sums, batch, N, Wro, bro, (float*)d_out, C);
}